// Round 7
// baseline (490.994 us; speedup 1.0000x reference)
//
#include <hip/hip_runtime.h>
#include <stdint.h>
#include <math.h>

// RPN proposal filtering: decode -> clip -> validity mask -> stable top-2000
// -> greedy NMS (IoU > 0.7) -> first 1000 kept -> (B, 1000, 5).
//
// R7: k_scanout (109 us: serial per-row scan, ~130 cyc/row on a 16-wave
// grid) rewritten with in-register chunk resolution: per 64-row chunk, the
// keep-set is resolved from a register-resident diagonal via ffs/readlane
// (~10 cyc per kept row), then one branchless OR pass folds kept rows' mask
// words into `removed`. Tiles double-buffered one chunk ahead. Greedy
// semantics identical (ascending leaders, forward suppression, -inf rows
// suppress but don't count, early exit at POST_NMS kept).

#define IMGF 1024.0f
#define PRE_NMS 2000
#define POST_NMS 1000
#define NMS_THR 0.7f
#define MIN_SZ 16.0f
#define CAP 4096          // candidate buffer per batch
#define SEL 2048          // padded selection stride (>= PRE_NMS)
#define NW (SEL / 64)     // 32 mask words per row
#define CNT_STRIDE 32     // u32s per batch for counters (128 B -> own line)
#define KEY_NEGINF 0x007FFFFFu  // f2key(-inf)
#define MAXCHUNK 12

// Order-preserving float -> u32 key (all floats incl. -inf totally ordered).
__device__ __forceinline__ uint32_t f2key(float f) {
  uint32_t u = __float_as_uint(f);
  return (u & 0x80000000u) ? ~u : (u | 0x80000000u);
}
__device__ __forceinline__ float key2f(uint32_t k) {
  uint32_t u = (k & 0x80000000u) ? (k & 0x7FFFFFFFu) : ~k;
  return __uint_as_float(u);
}

__device__ __forceinline__ unsigned long long readlane_u64(unsigned long long v,
                                                           int lane) {
  unsigned int lo = __builtin_amdgcn_readlane((unsigned int)v, lane);
  unsigned int hi = __builtin_amdgcn_readlane((unsigned int)(v >> 32), lane);
  return ((unsigned long long)hi << 32) | lo;
}

// Mirrors reference _decode + clip, fp32.
__device__ __forceinline__ float4 decode_clip(float4 anc, float4 dlt) {
  float aw = anc.z - anc.x;
  float ah = anc.w - anc.y;
  float ax = anc.x + 0.5f * aw;
  float ay = anc.y + 0.5f * ah;
  float dw = fminf(dlt.z, 4.0f);
  float dh = fminf(dlt.w, 4.0f);
  float px = dlt.x * aw + ax;
  float py = dlt.y * ah + ay;
  float pw = expf(dw) * aw;
  float ph = expf(dh) * ah;
  float x1 = px - 0.5f * pw, y1 = py - 0.5f * ph;
  float x2 = px + 0.5f * pw, y2 = py + 0.5f * ph;
  x1 = fminf(fmaxf(x1, 0.0f), IMGF);
  y1 = fminf(fmaxf(y1, 0.0f), IMGF);
  x2 = fminf(fmaxf(x2, 0.0f), IMGF);
  y2 = fminf(fmaxf(y2, 0.0f), IMGF);
  return make_float4(x1, y1, x2, y2);
}

// K1: decode -> masked-score key; per-block LDS coarse hist of key>>24
// (finite keys only), ballot-match wave aggregation, one aggregated global
// flush per block. grid = (bpb, B).
__global__ void k_decode(const float4* __restrict__ anchors,
                         const float4* __restrict__ deltas,
                         const float* __restrict__ scores,
                         uint32_t* __restrict__ keys,
                         uint32_t* __restrict__ chist,
                         int A, int chunks) {
  int b = blockIdx.y;
  int t = threadIdx.x;  // 256
  int lane = t & 63;
  __shared__ uint32_t shist[256];
  shist[t] = 0;
  __syncthreads();
  int base_a = blockIdx.x * (chunks * 256);
  for (int c = 0; c < chunks; c++) {
    int a = base_a + c * 256 + t;
    bool inb = a < A;
    int ac = inb ? a : (A - 1);
    size_t i = (size_t)b * A + ac;
    float4 box = decode_clip(anchors[ac], deltas[i]);
    bool valid = (box.z - box.x >= MIN_SZ) && (box.w - box.y >= MIN_SZ);
    float ms = valid ? scores[i] : -INFINITY;
    uint32_t k = f2key(ms);
    if (inb) keys[i] = k;
    uint32_t bucket = k >> 24;
    bool fin = inb && (k != KEY_NEGINF);
    // lanes with equal bucket -> one LDS atomic by the leader
    unsigned long long match = __ballot(fin);
#pragma unroll
    for (int bit = 0; bit < 8; bit++) {
      bool hb = (bucket >> bit) & 1;
      unsigned long long bb = __ballot(hb && fin);
      match &= hb ? bb : ~bb;
    }
    if (fin && (__ffsll((long long)match) - 1 == lane))
      atomicAdd(&shist[bucket], (uint32_t)__popcll(match));
  }
  __syncthreads();
  uint32_t v = shist[t];
  if (v) atomicAdd(&chist[b * 256 + t], v);
}

// K2: pick coarse bucket cb s.t. countAbove(cb) < PRE_NMS <= countAbove(cb)+chist[cb].
__global__ void k_coarse(const uint32_t* __restrict__ chist,
                         int* __restrict__ cbArr,
                         uint32_t* __restrict__ cumArr) {
  int b = blockIdx.x;
  int t = threadIdx.x;  // 256
  __shared__ uint32_t sA[256];
  sA[t] = chist[b * 256 + t];
  for (int d = 1; d < 256; d <<= 1) {  // inclusive suffix scan
    __syncthreads();
    uint32_t v = sA[t] + ((t + d < 256) ? sA[t + d] : 0u);
    __syncthreads();
    sA[t] = v;
  }
  __syncthreads();
  if (t == 0 && sA[0] < PRE_NMS) {  // degenerate: < PRE_NMS finite entries
    cbArr[b] = -1;
    cumArr[b] = 0;
  }
  uint32_t nxt = (t < 255) ? sA[t + 1] : 0u;
  if (sA[t] >= PRE_NMS && nxt < PRE_NMS) {
    cbArr[b] = t;
    cumArr[b] = nxt;  // count strictly above coarse bucket t
  }
}

// K3: fine hist of key bits[23:16] for elements whose coarse bucket == cb[b].
__global__ void k_fine(const uint32_t* __restrict__ keys,
                       const int* __restrict__ cbArr,
                       uint32_t* __restrict__ fhist,
                       int A, int chunks) {
  int b = blockIdx.y;
  int t = threadIdx.x;  // 256
  int cb = cbArr[b];
  if (cb < 0) return;
  __shared__ uint32_t shist[256];
  shist[t] = 0;
  __syncthreads();
  int base_a = blockIdx.x * (chunks * 256);
  uint32_t cbu = (uint32_t)cb;
  for (int c = 0; c < chunks; c++) {
    int a = base_a + c * 256 + t;
    if (a >= A) break;
    uint32_t k = keys[(size_t)b * A + a];
    if ((k >> 24) == cbu && k != KEY_NEGINF)
      atomicAdd(&shist[(k >> 16) & 0xFFu], 1u);
  }
  __syncthreads();
  uint32_t v = shist[t];
  if (v) atomicAdd(&fhist[b * 256 + t], v);
}

// K4: final 16-bit threshold beta = (cb<<8)|d:
// count(key>>16 > beta) < PRE_NMS <= count(key>>16 >= beta), finite keys only.
__global__ void k_thresh(const uint32_t* __restrict__ fhist,
                         const int* __restrict__ cbArr,
                         const uint32_t* __restrict__ cumArr,
                         uint32_t* __restrict__ thresh,
                         uint32_t* __restrict__ cnts) {
  int b = blockIdx.x;
  int t = threadIdx.x;  // 256
  __shared__ uint32_t sA[256];
  if (t < 2) cnts[b * CNT_STRIDE + t] = 0;
  int cb = cbArr[b];
  if (cb < 0) {
    if (t == 0) thresh[b] = 0u;
    return;
  }
  uint32_t cumAbove = cumArr[b];
  sA[t] = fhist[b * 256 + t];
  for (int d = 1; d < 256; d <<= 1) {
    __syncthreads();
    uint32_t v = sA[t] + ((t + d < 256) ? sA[t + d] : 0u);
    __syncthreads();
    sA[t] = v;
  }
  __syncthreads();
  uint32_t nxt = (t < 255) ? sA[t + 1] : 0u;
  if (cumAbove + sA[t] >= PRE_NMS && cumAbove + nxt < PRE_NMS)
    thresh[b] = (uint32_t)((cb << 8) | t);
}

// K5: gather candidate KEYS ONLY (8B each), block-aggregated atomics: one
// atomicAdd per category per block. Strictly-above fills [0, c1); ties fill
// from CAP-1 downward; overflow ties dropped (only above 2096 ties/batch).
__global__ void k_gather(const uint32_t* __restrict__ keys,
                         const uint32_t* __restrict__ thresh,
                         uint32_t* __restrict__ cnts,
                         unsigned long long* __restrict__ cand_sort,
                         int A, int chunks) {
  int b = blockIdx.y;
  int t = threadIdx.x;  // 256
  int lane = t & 63;
  int w = t >> 6;  // wave 0..3
  __shared__ unsigned long long s_mA[MAXCHUNK * 4], s_mT[MAXCHUNK * 4];
  __shared__ uint32_t s_offA[MAXCHUNK * 4], s_offT[MAXCHUNK * 4];
  __shared__ uint32_t s_cA[MAXCHUNK * 4], s_cT[MAXCHUNK * 4];
  __shared__ uint32_t s_baseA, s_baseT;
  uint32_t beta = thresh[b];
  uint32_t kreg[MAXCHUNK];
  int base_a = blockIdx.x * (chunks * 256);
  for (int c = 0; c < chunks; c++) {
    int a = base_a + c * 256 + t;
    bool inb = a < A;
    uint32_t k = inb ? keys[(size_t)b * A + a] : KEY_NEGINF;
    kreg[c] = k;
    uint32_t bk = k >> 16;
    bool fin = (k != KEY_NEGINF);
    unsigned long long mA = __ballot(fin && (bk > beta));
    unsigned long long mT = __ballot(fin && (bk == beta));
    if (lane == 0) {
      s_mA[c * 4 + w] = mA;
      s_mT[c * 4 + w] = mT;
    }
  }
  __syncthreads();
  if (t < chunks * 4) {
    s_cA[t] = (uint32_t)__popcll(s_mA[t]);
    s_cT[t] = (uint32_t)__popcll(s_mT[t]);
  }
  __syncthreads();
  if (t == 0) {  // serial scan over <=44 entries, then ONE atomic per category
    uint32_t accA = 0, accT = 0;
    for (int id = 0; id < chunks * 4; id++) {
      s_offA[id] = accA;
      accA += s_cA[id];
      s_offT[id] = accT;
      accT += s_cT[id];
    }
    s_baseA = accA ? atomicAdd(&cnts[b * CNT_STRIDE + 0], accA) : 0u;
    s_baseT = accT ? atomicAdd(&cnts[b * CNT_STRIDE + 1], accT) : 0u;
  }
  __syncthreads();
  uint32_t baseA = s_baseA, baseT = s_baseT;
  unsigned long long lower = ((unsigned long long)1 << lane) - 1;
  for (int c = 0; c < chunks; c++) {
    int id = c * 4 + w;
    unsigned long long mA = s_mA[id], mT = s_mT[id];
    bool above = (mA >> lane) & 1;
    bool tie = (mT >> lane) & 1;
    if (!(above || tie)) continue;
    int pos;
    if (above) {
      pos = (int)(baseA + s_offA[id] + (uint32_t)__popcll(mA & lower));
      if (pos >= PRE_NMS) continue;  // defensive; cannot happen
    } else {
      pos = CAP - 1 - (int)(baseT + s_offT[id] + (uint32_t)__popcll(mT & lower));
      if (pos < PRE_NMS) continue;  // drop overflow ties
    }
    int a = base_a + c * 256 + t;
    // sort key: (score_key desc, anchor index asc) via descending u64 order
    cand_sort[(size_t)b * CAP + pos] =
        ((unsigned long long)kreg[c] << 32) | (uint32_t)(~(uint32_t)a);
  }
}

// K6a: default-fill selection (pads for degenerate batches; overwritten by
// k_rank for every live rank < SEL). grid = (SEL/256, B).
__global__ void k_fillsel(float4* __restrict__ sel_box,
                          float* __restrict__ sel_score) {
  int b = blockIdx.y;
  int r = blockIdx.x * 256 + threadIdx.x;
  sel_score[(size_t)b * SEL + r] = -INFINITY;
  sel_box[(size_t)b * SEL + r] = make_float4(0.0f, 0.0f, 0.0f, 0.0f);
}

// K6b: enumeration sort. Keys are strictly distinct ((score_key, ~anchor)),
// so rank = #{keys > mine} is the exact descending-sorted position. Each
// thread owns one slot, streams the batch's live slots through LDS broadcast
// tiles, and (if rank < SEL) decodes its box from the embedded anchor index.
// grid = (CAP/256, B).
__global__ void k_rank(const unsigned long long* __restrict__ cand_sort,
                       const uint32_t* __restrict__ cnts,
                       const float4* __restrict__ anchors,
                       const float4* __restrict__ deltas,
                       float4* __restrict__ sel_box,
                       float* __restrict__ sel_score, int A) {
  int b = blockIdx.y;
  int t = threadIdx.x;  // 256
  uint32_t c1 = cnts[b * CNT_STRIDE + 0];
  if (c1 > PRE_NMS) c1 = PRE_NMS;
  uint32_t c2 = cnts[b * CNT_STRIDE + 1];
  if (c2 > CAP - PRE_NMS) c2 = CAP - PRE_NMS;
  int loTie = CAP - (int)c2;
  int bs = blockIdx.x * 256;
  if (bs >= (int)c1 && bs + 256 <= loTie) return;  // block fully in dead gap
  int s = bs + t;
  bool live = (s < (int)c1) || (s >= loTie);
  unsigned long long myKey = live ? cand_sort[(size_t)b * CAP + s] : 0ull;
  __shared__ unsigned long long tile[256];
  int rank = 0;
  for (int ts = 0; ts < CAP; ts += 256) {  // tile-skip is block-uniform
    if (ts >= (int)c1 && ts + 256 <= loTie) continue;
    int idx = ts + t;
    bool lv = (idx < (int)c1) || (idx >= loTie);
    __syncthreads();
    tile[t] = lv ? cand_sort[(size_t)b * CAP + idx] : 0ull;
    __syncthreads();
    if (live) {
#pragma unroll 8
      for (int j = 0; j < 256; j++) rank += (tile[j] > myKey) ? 1 : 0;
    }
  }
  if (live && rank < SEL) {
    uint32_t a = ~((uint32_t)myKey);
    float4 box = decode_clip(anchors[a], deltas[(size_t)b * A + a]);
    sel_score[(size_t)b * SEL + rank] = key2f((uint32_t)(myKey >> 32));
    sel_box[(size_t)b * SEL + rank] = box;
  }
}

// K7: suppression bitmask. mask[b][i][jb] bit jj set iff j = jb*64+jj > i,
// j < PRE_NMS, IoU(box_i, box_j) > NMS_THR. Rows in [PRE_NMS, SEL) zeroed
// so k_scanout never reads unwritten workspace.
__global__ void k_nmsmask(const float4* __restrict__ sel_box,
                          unsigned long long* __restrict__ mask) {
  int jb = blockIdx.x;  // col block
  int ib = blockIdx.y;  // row block
  int b = blockIdx.z;
  int t = threadIdx.x;  // 64
  int i = ib * 64 + t;
  if (jb < ib) {  // uniform per block; entire col tile is <= all rows
    mask[((size_t)b * SEL + i) * NW + jb] = 0ull;
    return;
  }
  __shared__ float4 cb[64];
  __shared__ float careb[64];
  int j0 = jb * 64;
  float4 cbx = sel_box[(size_t)b * SEL + j0 + t];
  cb[t] = cbx;
  careb[t] = (cbx.z - cbx.x) * (cbx.w - cbx.y);
  __syncthreads();
  if (i >= PRE_NMS) {  // pad rows: write zeros, never leave stale poison
    mask[((size_t)b * SEL + i) * NW + jb] = 0ull;
    return;
  }
  float4 a = sel_box[(size_t)b * SEL + i];
  float area_a = (a.z - a.x) * (a.w - a.y);
  unsigned long long bits = 0ull;
  int jmax = min(64, PRE_NMS - j0);
  for (int jj = 0; jj < jmax; jj++) {
    int j = j0 + jj;
    if (j <= i) continue;
    float4 bb = cb[jj];
    float ltx = fmaxf(a.x, bb.x), lty = fmaxf(a.y, bb.y);
    float rbx = fminf(a.z, bb.z), rby = fminf(a.w, bb.w);
    float w = fmaxf(rbx - ltx, 0.0f), hgt = fmaxf(rby - lty, 0.0f);
    float inter = w * hgt;
    float iou = inter / (area_a + careb[jj] - inter + 1e-6f);
    if (iou > NMS_THR) bits |= (1ull << jj);
  }
  mask[((size_t)b * SEL + i) * NW + jb] = bits;
}

// K8 (R7): one wave per batch, in-register chunk resolution.
// Lane t holds mask word (t&31) of rows (t>>5)*32+j (j<32) for the current
// chunk, the diagonal vector (lane r = row r's word `chunk`), and the 64
// scores; all double-buffered one chunk ahead. Keep-set resolved via
// ffs/readlane on wave-uniform scalars; one branchless OR pass updates
// `removed` (lane t owns word t&31; halves combined via shfl_xor 32).
__global__ void k_scanout(const float4* __restrict__ sel_box,
                          const float* __restrict__ sel_score,
                          const unsigned long long* __restrict__ mask,
                          float* __restrict__ out) {
  int b = blockIdx.x;
  int t = threadIdx.x;  // 64 = 1 wave
  int tw = t & 31;
  int half = t >> 5;
  __shared__ uint32_t keptList[POST_NMS];
  unsigned long long removed = 0ull;  // lane t owns word tw (complete copy)
  int kc = 0;
  const unsigned long long* mbase = mask + (size_t)b * SEL * NW;
  const int NCH = (PRE_NMS + 63) / 64;  // 32 chunks (last rmax=16)

  unsigned long long m0[32], m1[32];
  unsigned long long d0 = 0, d1 = 0;
  uint32_t s0 = 0, s1 = 0;
  {  // prime chunk 0
#pragma unroll
    for (int j = 0; j < 32; j++) m0[j] = mbase[(half * 32 + j) * NW + tw];
    d0 = mbase[t * NW + 0];
    s0 = __float_as_uint(sel_score[(size_t)b * SEL + t]);
  }
  for (int chunk = 0; chunk < NCH; chunk++) {
    bool even = !(chunk & 1);
    if (chunk + 1 < NCH) {  // prefetch next chunk into the other buffer
      const unsigned long long* cbn = mbase + (size_t)(chunk + 1) * 64 * NW;
      if (even) {
#pragma unroll
        for (int j = 0; j < 32; j++) m1[j] = cbn[(half * 32 + j) * NW + tw];
        d1 = cbn[t * NW + (chunk + 1)];
        s1 = __float_as_uint(sel_score[(size_t)b * SEL + (chunk + 1) * 64 + t]);
      } else {
#pragma unroll
        for (int j = 0; j < 32; j++) m0[j] = cbn[(half * 32 + j) * NW + tw];
        d0 = cbn[t * NW + (chunk + 1)];
        s0 = __float_as_uint(sel_score[(size_t)b * SEL + (chunk + 1) * 64 + t]);
      }
    }
    unsigned long long diag = even ? d0 : d1;
    uint32_t scb_all = even ? s0 : s1;
    int rmax = PRE_NMS - chunk * 64;
    if (rmax > 64) rmax = 64;
    unsigned long long alive = ~readlane_u64(removed, chunk);
    if (rmax < 64) alive &= (((unsigned long long)1 << rmax) - 1);
    unsigned long long keepm = 0ull;
    while (alive) {
      int r = __ffsll((long long)alive) - 1;
      keepm |= ((unsigned long long)1 << r);
      alive &= ~((unsigned long long)1 << r);
      uint32_t scb = __builtin_amdgcn_readlane(scb_all, r);
      if (scb != 0xFF800000u) {  // score != -inf: counted & output
        if (t == 0) keptList[kc] = (uint32_t)(chunk * 64 + r);
        kc++;
        if (kc == POST_NMS) goto writeout;
      }
      alive &= ~readlane_u64(diag, r);  // forward in-chunk suppression
    }
    // OR phase: fold kept rows' mask words into removed.
    {
      uint32_t km = half ? (uint32_t)(keepm >> 32) : (uint32_t)keepm;
      unsigned long long partial = 0ull;
      if (even) {
#pragma unroll
        for (int j = 0; j < 32; j++)
          partial |= ((km >> j) & 1u) ? m0[j] : 0ull;
      } else {
#pragma unroll
        for (int j = 0; j < 32; j++)
          partial |= ((km >> j) & 1u) ? m1[j] : 0ull;
      }
      removed |= partial | (unsigned long long)__shfl_xor((long long)partial, 32);
    }
  }
writeout:
  __syncthreads();
  for (int r = t; r < POST_NMS; r += 64) {
    float4 bx = make_float4(0.0f, 0.0f, 0.0f, 0.0f);
    float sc = 0.0f;
    if (r < kc) {
      int i = (int)keptList[r];
      bx = sel_box[(size_t)b * SEL + i];
      sc = sel_score[(size_t)b * SEL + i];
    }
    float* o = out + ((size_t)b * POST_NMS + r) * 5;
    o[0] = bx.x;
    o[1] = bx.y;
    o[2] = bx.z;
    o[3] = bx.w;
    o[4] = sc;
  }
}

extern "C" void kernel_launch(void* const* d_in, const int* in_sizes, int n_in,
                              void* d_out, int out_size, void* d_ws, size_t ws_size,
                              hipStream_t stream) {
  const float* anchors = (const float*)d_in[0];  // (A, 4)
  const float* deltas = (const float*)d_in[1];   // (B, A, 4)
  const float* scores = (const float*)d_in[2];   // (B, A)
  int A = in_sizes[0] / 4;
  int BA = in_sizes[2];
  int B = BA / A;
  float* out = (float*)d_out;

  char* ws = (char*)d_ws;
  size_t off = 0;
  uint32_t* keys = (uint32_t*)(ws + off);
  off += (size_t)BA * 4;
  uint32_t* chist = (uint32_t*)(ws + off);
  off += (size_t)B * 256 * 4;
  uint32_t* fhist = (uint32_t*)(ws + off);
  off += (size_t)B * 256 * 4;
  int* cbArr = (int*)(ws + off);
  off += (size_t)B * 4;
  uint32_t* cumArr = (uint32_t*)(ws + off);
  off += (size_t)B * 4;
  uint32_t* thresh = (uint32_t*)(ws + off);
  off += (size_t)B * 4;
  off = (off + 127) & ~(size_t)127;
  uint32_t* cnts = (uint32_t*)(ws + off);
  off += (size_t)B * CNT_STRIDE * 4;
  off = (off + 15) & ~(size_t)15;
  unsigned long long* cand_sort = (unsigned long long*)(ws + off);
  off += (size_t)B * CAP * 8;
  float4* sel_box = (float4*)(ws + off);
  off += (size_t)B * SEL * 16;
  float* sel_score = (float*)(ws + off);
  off += (size_t)B * SEL * 4;
  unsigned long long* mask = (unsigned long long*)(ws + off);
  off += (size_t)B * SEL * NW * 8;
  // total ~27 MB

  // Block geometry for per-batch streaming kernels: A = 261888 = 256*11*93.
  int chunks = (A % (256 * 11) == 0) ? 11 : 1;
  int bpb = (A + 256 * chunks - 1) / (256 * chunks);  // blocks per batch

  hipMemsetAsync(chist, 0, (size_t)B * 256 * 4 * 2, stream);  // chist+fhist
  k_decode<<<dim3(bpb, B), 256, 0, stream>>>((const float4*)anchors,
                                             (const float4*)deltas, scores,
                                             keys, chist, A, chunks);
  k_coarse<<<B, 256, 0, stream>>>(chist, cbArr, cumArr);
  k_fine<<<dim3(bpb, B), 256, 0, stream>>>(keys, cbArr, fhist, A, chunks);
  k_thresh<<<B, 256, 0, stream>>>(fhist, cbArr, cumArr, thresh, cnts);
  k_gather<<<dim3(bpb, B), 256, 0, stream>>>(keys, thresh, cnts, cand_sort, A,
                                             chunks);
  k_fillsel<<<dim3(SEL / 256, B), 256, 0, stream>>>(sel_box, sel_score);
  k_rank<<<dim3(CAP / 256, B), 256, 0, stream>>>(cand_sort, cnts,
                                                 (const float4*)anchors,
                                                 (const float4*)deltas,
                                                 sel_box, sel_score, A);
  k_nmsmask<<<dim3(NW, SEL / 64, B), 64, 0, stream>>>(sel_box, mask);
  k_scanout<<<B, 64, 0, stream>>>(sel_box, sel_score, mask, out);
}

// Round 8
// 433.073 us; speedup vs baseline: 1.1337x; 1.1337x over previous
//
#include <hip/hip_runtime.h>
#include <stdint.h>
#include <math.h>

// RPN proposal filtering: decode -> clip -> validity mask -> stable top-2000
// -> greedy NMS (IoU > 0.7) -> first 1000 kept -> (B, 1000, 5).
//
// R8: R7's chunk-resolution scanout was correct but spilled its 64-u64
// register tile to scratch (VGPR_Count=64 vs 128 needed -> 240 us, scratch
// writeback visible in WRITE_SIZE). Same algorithm, tile moved to LDS
// (2 x 16 KB double buffer, single wave so lgkmcnt ordering suffices, no
// barriers), prefetch regs bounded at 16 x ulonglong2 with
// __launch_bounds__(64,1) so nothing spills.

#define IMGF 1024.0f
#define PRE_NMS 2000
#define POST_NMS 1000
#define NMS_THR 0.7f
#define MIN_SZ 16.0f
#define CAP 4096          // candidate buffer per batch
#define SEL 2048          // padded selection stride (>= PRE_NMS)
#define NW (SEL / 64)     // 32 mask words per row
#define CNT_STRIDE 32     // u32s per batch for counters (128 B -> own line)
#define KEY_NEGINF 0x007FFFFFu  // f2key(-inf)
#define MAXCHUNK 12

// Order-preserving float -> u32 key (all floats incl. -inf totally ordered).
__device__ __forceinline__ uint32_t f2key(float f) {
  uint32_t u = __float_as_uint(f);
  return (u & 0x80000000u) ? ~u : (u | 0x80000000u);
}
__device__ __forceinline__ float key2f(uint32_t k) {
  uint32_t u = (k & 0x80000000u) ? (k & 0x7FFFFFFFu) : ~k;
  return __uint_as_float(u);
}

__device__ __forceinline__ unsigned long long readlane_u64(unsigned long long v,
                                                           int lane) {
  unsigned int lo = __builtin_amdgcn_readlane((unsigned int)v, lane);
  unsigned int hi = __builtin_amdgcn_readlane((unsigned int)(v >> 32), lane);
  return ((unsigned long long)hi << 32) | lo;
}

// Mirrors reference _decode + clip, fp32.
__device__ __forceinline__ float4 decode_clip(float4 anc, float4 dlt) {
  float aw = anc.z - anc.x;
  float ah = anc.w - anc.y;
  float ax = anc.x + 0.5f * aw;
  float ay = anc.y + 0.5f * ah;
  float dw = fminf(dlt.z, 4.0f);
  float dh = fminf(dlt.w, 4.0f);
  float px = dlt.x * aw + ax;
  float py = dlt.y * ah + ay;
  float pw = expf(dw) * aw;
  float ph = expf(dh) * ah;
  float x1 = px - 0.5f * pw, y1 = py - 0.5f * ph;
  float x2 = px + 0.5f * pw, y2 = py + 0.5f * ph;
  x1 = fminf(fmaxf(x1, 0.0f), IMGF);
  y1 = fminf(fmaxf(y1, 0.0f), IMGF);
  x2 = fminf(fmaxf(x2, 0.0f), IMGF);
  y2 = fminf(fmaxf(y2, 0.0f), IMGF);
  return make_float4(x1, y1, x2, y2);
}

// K1: decode -> masked-score key; per-block LDS coarse hist of key>>24
// (finite keys only), ballot-match wave aggregation, one aggregated global
// flush per block. grid = (bpb, B).
__global__ void k_decode(const float4* __restrict__ anchors,
                         const float4* __restrict__ deltas,
                         const float* __restrict__ scores,
                         uint32_t* __restrict__ keys,
                         uint32_t* __restrict__ chist,
                         int A, int chunks) {
  int b = blockIdx.y;
  int t = threadIdx.x;  // 256
  int lane = t & 63;
  __shared__ uint32_t shist[256];
  shist[t] = 0;
  __syncthreads();
  int base_a = blockIdx.x * (chunks * 256);
  for (int c = 0; c < chunks; c++) {
    int a = base_a + c * 256 + t;
    bool inb = a < A;
    int ac = inb ? a : (A - 1);
    size_t i = (size_t)b * A + ac;
    float4 box = decode_clip(anchors[ac], deltas[i]);
    bool valid = (box.z - box.x >= MIN_SZ) && (box.w - box.y >= MIN_SZ);
    float ms = valid ? scores[i] : -INFINITY;
    uint32_t k = f2key(ms);
    if (inb) keys[i] = k;
    uint32_t bucket = k >> 24;
    bool fin = inb && (k != KEY_NEGINF);
    // lanes with equal bucket -> one LDS atomic by the leader
    unsigned long long match = __ballot(fin);
#pragma unroll
    for (int bit = 0; bit < 8; bit++) {
      bool hb = (bucket >> bit) & 1;
      unsigned long long bb = __ballot(hb && fin);
      match &= hb ? bb : ~bb;
    }
    if (fin && (__ffsll((long long)match) - 1 == lane))
      atomicAdd(&shist[bucket], (uint32_t)__popcll(match));
  }
  __syncthreads();
  uint32_t v = shist[t];
  if (v) atomicAdd(&chist[b * 256 + t], v);
}

// K2: pick coarse bucket cb s.t. countAbove(cb) < PRE_NMS <= countAbove(cb)+chist[cb].
__global__ void k_coarse(const uint32_t* __restrict__ chist,
                         int* __restrict__ cbArr,
                         uint32_t* __restrict__ cumArr) {
  int b = blockIdx.x;
  int t = threadIdx.x;  // 256
  __shared__ uint32_t sA[256];
  sA[t] = chist[b * 256 + t];
  for (int d = 1; d < 256; d <<= 1) {  // inclusive suffix scan
    __syncthreads();
    uint32_t v = sA[t] + ((t + d < 256) ? sA[t + d] : 0u);
    __syncthreads();
    sA[t] = v;
  }
  __syncthreads();
  if (t == 0 && sA[0] < PRE_NMS) {  // degenerate: < PRE_NMS finite entries
    cbArr[b] = -1;
    cumArr[b] = 0;
  }
  uint32_t nxt = (t < 255) ? sA[t + 1] : 0u;
  if (sA[t] >= PRE_NMS && nxt < PRE_NMS) {
    cbArr[b] = t;
    cumArr[b] = nxt;  // count strictly above coarse bucket t
  }
}

// K3: fine hist of key bits[23:16] for elements whose coarse bucket == cb[b].
__global__ void k_fine(const uint32_t* __restrict__ keys,
                       const int* __restrict__ cbArr,
                       uint32_t* __restrict__ fhist,
                       int A, int chunks) {
  int b = blockIdx.y;
  int t = threadIdx.x;  // 256
  int cb = cbArr[b];
  if (cb < 0) return;
  __shared__ uint32_t shist[256];
  shist[t] = 0;
  __syncthreads();
  int base_a = blockIdx.x * (chunks * 256);
  uint32_t cbu = (uint32_t)cb;
  for (int c = 0; c < chunks; c++) {
    int a = base_a + c * 256 + t;
    if (a >= A) break;
    uint32_t k = keys[(size_t)b * A + a];
    if ((k >> 24) == cbu && k != KEY_NEGINF)
      atomicAdd(&shist[(k >> 16) & 0xFFu], 1u);
  }
  __syncthreads();
  uint32_t v = shist[t];
  if (v) atomicAdd(&fhist[b * 256 + t], v);
}

// K4: final 16-bit threshold beta = (cb<<8)|d:
// count(key>>16 > beta) < PRE_NMS <= count(key>>16 >= beta), finite keys only.
__global__ void k_thresh(const uint32_t* __restrict__ fhist,
                         const int* __restrict__ cbArr,
                         const uint32_t* __restrict__ cumArr,
                         uint32_t* __restrict__ thresh,
                         uint32_t* __restrict__ cnts) {
  int b = blockIdx.x;
  int t = threadIdx.x;  // 256
  __shared__ uint32_t sA[256];
  if (t < 2) cnts[b * CNT_STRIDE + t] = 0;
  int cb = cbArr[b];
  if (cb < 0) {
    if (t == 0) thresh[b] = 0u;
    return;
  }
  uint32_t cumAbove = cumArr[b];
  sA[t] = fhist[b * 256 + t];
  for (int d = 1; d < 256; d <<= 1) {
    __syncthreads();
    uint32_t v = sA[t] + ((t + d < 256) ? sA[t + d] : 0u);
    __syncthreads();
    sA[t] = v;
  }
  __syncthreads();
  uint32_t nxt = (t < 255) ? sA[t + 1] : 0u;
  if (cumAbove + sA[t] >= PRE_NMS && cumAbove + nxt < PRE_NMS)
    thresh[b] = (uint32_t)((cb << 8) | t);
}

// K5: gather candidate KEYS ONLY (8B each), block-aggregated atomics: one
// atomicAdd per category per block. Strictly-above fills [0, c1); ties fill
// from CAP-1 downward; overflow ties dropped (only above 2096 ties/batch).
__global__ void k_gather(const uint32_t* __restrict__ keys,
                         const uint32_t* __restrict__ thresh,
                         uint32_t* __restrict__ cnts,
                         unsigned long long* __restrict__ cand_sort,
                         int A, int chunks) {
  int b = blockIdx.y;
  int t = threadIdx.x;  // 256
  int lane = t & 63;
  int w = t >> 6;  // wave 0..3
  __shared__ unsigned long long s_mA[MAXCHUNK * 4], s_mT[MAXCHUNK * 4];
  __shared__ uint32_t s_offA[MAXCHUNK * 4], s_offT[MAXCHUNK * 4];
  __shared__ uint32_t s_cA[MAXCHUNK * 4], s_cT[MAXCHUNK * 4];
  __shared__ uint32_t s_baseA, s_baseT;
  uint32_t beta = thresh[b];
  uint32_t kreg[MAXCHUNK];
  int base_a = blockIdx.x * (chunks * 256);
  for (int c = 0; c < chunks; c++) {
    int a = base_a + c * 256 + t;
    bool inb = a < A;
    uint32_t k = inb ? keys[(size_t)b * A + a] : KEY_NEGINF;
    kreg[c] = k;
    uint32_t bk = k >> 16;
    bool fin = (k != KEY_NEGINF);
    unsigned long long mA = __ballot(fin && (bk > beta));
    unsigned long long mT = __ballot(fin && (bk == beta));
    if (lane == 0) {
      s_mA[c * 4 + w] = mA;
      s_mT[c * 4 + w] = mT;
    }
  }
  __syncthreads();
  if (t < chunks * 4) {
    s_cA[t] = (uint32_t)__popcll(s_mA[t]);
    s_cT[t] = (uint32_t)__popcll(s_mT[t]);
  }
  __syncthreads();
  if (t == 0) {  // serial scan over <=44 entries, then ONE atomic per category
    uint32_t accA = 0, accT = 0;
    for (int id = 0; id < chunks * 4; id++) {
      s_offA[id] = accA;
      accA += s_cA[id];
      s_offT[id] = accT;
      accT += s_cT[id];
    }
    s_baseA = accA ? atomicAdd(&cnts[b * CNT_STRIDE + 0], accA) : 0u;
    s_baseT = accT ? atomicAdd(&cnts[b * CNT_STRIDE + 1], accT) : 0u;
  }
  __syncthreads();
  uint32_t baseA = s_baseA, baseT = s_baseT;
  unsigned long long lower = ((unsigned long long)1 << lane) - 1;
  for (int c = 0; c < chunks; c++) {
    int id = c * 4 + w;
    unsigned long long mA = s_mA[id], mT = s_mT[id];
    bool above = (mA >> lane) & 1;
    bool tie = (mT >> lane) & 1;
    if (!(above || tie)) continue;
    int pos;
    if (above) {
      pos = (int)(baseA + s_offA[id] + (uint32_t)__popcll(mA & lower));
      if (pos >= PRE_NMS) continue;  // defensive; cannot happen
    } else {
      pos = CAP - 1 - (int)(baseT + s_offT[id] + (uint32_t)__popcll(mT & lower));
      if (pos < PRE_NMS) continue;  // drop overflow ties
    }
    int a = base_a + c * 256 + t;
    // sort key: (score_key desc, anchor index asc) via descending u64 order
    cand_sort[(size_t)b * CAP + pos] =
        ((unsigned long long)kreg[c] << 32) | (uint32_t)(~(uint32_t)a);
  }
}

// K6a: default-fill selection (pads for degenerate batches; overwritten by
// k_rank for every live rank < SEL). grid = (SEL/256, B).
__global__ void k_fillsel(float4* __restrict__ sel_box,
                          float* __restrict__ sel_score) {
  int b = blockIdx.y;
  int r = blockIdx.x * 256 + threadIdx.x;
  sel_score[(size_t)b * SEL + r] = -INFINITY;
  sel_box[(size_t)b * SEL + r] = make_float4(0.0f, 0.0f, 0.0f, 0.0f);
}

// K6b: enumeration sort. Keys are strictly distinct ((score_key, ~anchor)),
// so rank = #{keys > mine} is the exact descending-sorted position. Each
// thread owns one slot, streams the batch's live slots through LDS broadcast
// tiles, and (if rank < SEL) decodes its box from the embedded anchor index.
// grid = (CAP/256, B).
__global__ void k_rank(const unsigned long long* __restrict__ cand_sort,
                       const uint32_t* __restrict__ cnts,
                       const float4* __restrict__ anchors,
                       const float4* __restrict__ deltas,
                       float4* __restrict__ sel_box,
                       float* __restrict__ sel_score, int A) {
  int b = blockIdx.y;
  int t = threadIdx.x;  // 256
  uint32_t c1 = cnts[b * CNT_STRIDE + 0];
  if (c1 > PRE_NMS) c1 = PRE_NMS;
  uint32_t c2 = cnts[b * CNT_STRIDE + 1];
  if (c2 > CAP - PRE_NMS) c2 = CAP - PRE_NMS;
  int loTie = CAP - (int)c2;
  int bs = blockIdx.x * 256;
  if (bs >= (int)c1 && bs + 256 <= loTie) return;  // block fully in dead gap
  int s = bs + t;
  bool live = (s < (int)c1) || (s >= loTie);
  unsigned long long myKey = live ? cand_sort[(size_t)b * CAP + s] : 0ull;
  __shared__ unsigned long long tile[256];
  int rank = 0;
  for (int ts = 0; ts < CAP; ts += 256) {  // tile-skip is block-uniform
    if (ts >= (int)c1 && ts + 256 <= loTie) continue;
    int idx = ts + t;
    bool lv = (idx < (int)c1) || (idx >= loTie);
    __syncthreads();
    tile[t] = lv ? cand_sort[(size_t)b * CAP + idx] : 0ull;
    __syncthreads();
    if (live) {
#pragma unroll 8
      for (int j = 0; j < 256; j++) rank += (tile[j] > myKey) ? 1 : 0;
    }
  }
  if (live && rank < SEL) {
    uint32_t a = ~((uint32_t)myKey);
    float4 box = decode_clip(anchors[a], deltas[(size_t)b * A + a]);
    sel_score[(size_t)b * SEL + rank] = key2f((uint32_t)(myKey >> 32));
    sel_box[(size_t)b * SEL + rank] = box;
  }
}

// K7: suppression bitmask. mask[b][i][jb] bit jj set iff j = jb*64+jj > i,
// j < PRE_NMS, IoU(box_i, box_j) > NMS_THR. Rows in [PRE_NMS, SEL) zeroed
// so k_scanout never reads unwritten workspace.
__global__ void k_nmsmask(const float4* __restrict__ sel_box,
                          unsigned long long* __restrict__ mask) {
  int jb = blockIdx.x;  // col block
  int ib = blockIdx.y;  // row block
  int b = blockIdx.z;
  int t = threadIdx.x;  // 64
  int i = ib * 64 + t;
  if (jb < ib) {  // uniform per block; entire col tile is <= all rows
    mask[((size_t)b * SEL + i) * NW + jb] = 0ull;
    return;
  }
  __shared__ float4 cb[64];
  __shared__ float careb[64];
  int j0 = jb * 64;
  float4 cbx = sel_box[(size_t)b * SEL + j0 + t];
  cb[t] = cbx;
  careb[t] = (cbx.z - cbx.x) * (cbx.w - cbx.y);
  __syncthreads();
  if (i >= PRE_NMS) {  // pad rows: write zeros, never leave stale poison
    mask[((size_t)b * SEL + i) * NW + jb] = 0ull;
    return;
  }
  float4 a = sel_box[(size_t)b * SEL + i];
  float area_a = (a.z - a.x) * (a.w - a.y);
  unsigned long long bits = 0ull;
  int jmax = min(64, PRE_NMS - j0);
  for (int jj = 0; jj < jmax; jj++) {
    int j = j0 + jj;
    if (j <= i) continue;
    float4 bb = cb[jj];
    float ltx = fmaxf(a.x, bb.x), lty = fmaxf(a.y, bb.y);
    float rbx = fminf(a.z, bb.z), rby = fminf(a.w, bb.w);
    float w = fmaxf(rbx - ltx, 0.0f), hgt = fmaxf(rby - lty, 0.0f);
    float inter = w * hgt;
    float iou = inter / (area_a + careb[jj] - inter + 1e-6f);
    if (iou > NMS_THR) bits |= (1ull << jj);
  }
  mask[((size_t)b * SEL + i) * NW + jb] = bits;
}

// K8 (R8): one wave per batch; chunk tile in LDS double buffer.
// Per chunk: keep-set resolved from register diag via ffs/readlane (~12 cyc
// per leader, suppressed rows skipped free); OR phase folds kept rows' words
// from LDS into `removed` (lane t owns word t&31, halves merged via
// shfl_xor 32). Next chunk's tile prefetched into 16 ulonglong2 regs at top,
// ds_written at bottom (vmcnt drain overlaps the chunk body). Single wave:
// no barriers, lgkmcnt ordering suffices.
__global__ void __launch_bounds__(64, 1) k_scanout(
    const float4* __restrict__ sel_box,
    const float* __restrict__ sel_score,
    const unsigned long long* __restrict__ mask,
    float* __restrict__ out) {
  int b = blockIdx.x;
  int t = threadIdx.x;  // 64 = 1 wave
  int tw = t & 31;
  __shared__ unsigned long long sTile[2][64 * NW];  // 2 x 16 KB
  __shared__ uint32_t keptList[POST_NMS];
  const unsigned long long* mbase = mask + (size_t)b * SEL * NW;
  unsigned long long removed = 0ull;  // lane t holds word tw (dup per half)
  int kc = 0;
  const int NCH = (PRE_NMS + 63) / 64;  // 32; diag word index == chunk < NW

  typedef ulonglong2 ull2;
  {  // prime tile 0
    const ull2* g0 = (const ull2*)mbase;
    ull2* d0 = (ull2*)sTile[0];
#pragma unroll
    for (int q = 0; q < 16; q++) d0[q * 64 + t] = g0[q * 64 + t];
  }
  uint32_t s_cur = __float_as_uint(sel_score[(size_t)b * SEL + t]);

  for (int chunk = 0; chunk < NCH; chunk++) {
    int buf = chunk & 1;
    ull2 stg[16];
    uint32_t s_nxt = 0;
    bool hasNext = (chunk + 1 < NCH);
    if (hasNext) {  // issue next-tile global loads now, ds_write at bottom
      const ull2* gn = (const ull2*)(mbase + (size_t)(chunk + 1) * 64 * NW);
#pragma unroll
      for (int q = 0; q < 16; q++) stg[q] = gn[q * 64 + t];
      s_nxt = __float_as_uint(sel_score[(size_t)b * SEL + (chunk + 1) * 64 + t]);
    }
    // diag: lane r = row (chunk*64+r)'s word `chunk` (in-chunk suppression bits)
    unsigned long long diag = sTile[buf][t * NW + chunk];
    int rmax = PRE_NMS - chunk * 64;
    if (rmax > 64) rmax = 64;
    unsigned long long alive = ~readlane_u64(removed, chunk);
    if (rmax < 64) alive &= (((unsigned long long)1 << rmax) - 1);
    unsigned long long keepm = 0ull;
    while (alive) {
      int r = __ffsll((long long)alive) - 1;
      keepm |= ((unsigned long long)1 << r);
      alive &= ~((unsigned long long)1 << r);
      uint32_t scb = __builtin_amdgcn_readlane(s_cur, r);
      if (scb != 0xFF800000u) {  // score != -inf: counted & output
        if (t == 0) keptList[kc] = (uint32_t)(chunk * 64 + r);
        kc++;
        if (kc == POST_NMS) goto writeout;
      }
      alive &= ~readlane_u64(diag, r);  // forward in-chunk suppression
    }
    {  // OR phase: fold kept rows' words (from LDS) into removed
      unsigned long long partial = 0ull;
      unsigned long long km = keepm;
      while (km) {
        int r = __ffsll((long long)km) - 1;
        km &= km - 1;
        partial |= sTile[buf][r * NW + tw];
      }
      removed |=
          partial | (unsigned long long)__shfl_xor((long long)partial, 32);
    }
    if (hasNext) {  // commit prefetched tile to the other buffer
      ull2* dn = (ull2*)sTile[buf ^ 1];
#pragma unroll
      for (int q = 0; q < 16; q++) dn[q * 64 + t] = stg[q];
      s_cur = s_nxt;
    }
  }
writeout:
  __syncthreads();
  for (int r = t; r < POST_NMS; r += 64) {
    float4 bx = make_float4(0.0f, 0.0f, 0.0f, 0.0f);
    float sc = 0.0f;
    if (r < kc) {
      int i = (int)keptList[r];
      bx = sel_box[(size_t)b * SEL + i];
      sc = sel_score[(size_t)b * SEL + i];
    }
    float* o = out + ((size_t)b * POST_NMS + r) * 5;
    o[0] = bx.x;
    o[1] = bx.y;
    o[2] = bx.z;
    o[3] = bx.w;
    o[4] = sc;
  }
}

extern "C" void kernel_launch(void* const* d_in, const int* in_sizes, int n_in,
                              void* d_out, int out_size, void* d_ws, size_t ws_size,
                              hipStream_t stream) {
  const float* anchors = (const float*)d_in[0];  // (A, 4)
  const float* deltas = (const float*)d_in[1];   // (B, A, 4)
  const float* scores = (const float*)d_in[2];   // (B, A)
  int A = in_sizes[0] / 4;
  int BA = in_sizes[2];
  int B = BA / A;
  float* out = (float*)d_out;

  char* ws = (char*)d_ws;
  size_t off = 0;
  uint32_t* keys = (uint32_t*)(ws + off);
  off += (size_t)BA * 4;
  uint32_t* chist = (uint32_t*)(ws + off);
  off += (size_t)B * 256 * 4;
  uint32_t* fhist = (uint32_t*)(ws + off);
  off += (size_t)B * 256 * 4;
  int* cbArr = (int*)(ws + off);
  off += (size_t)B * 4;
  uint32_t* cumArr = (uint32_t*)(ws + off);
  off += (size_t)B * 4;
  uint32_t* thresh = (uint32_t*)(ws + off);
  off += (size_t)B * 4;
  off = (off + 127) & ~(size_t)127;
  uint32_t* cnts = (uint32_t*)(ws + off);
  off += (size_t)B * CNT_STRIDE * 4;
  off = (off + 15) & ~(size_t)15;
  unsigned long long* cand_sort = (unsigned long long*)(ws + off);
  off += (size_t)B * CAP * 8;
  float4* sel_box = (float4*)(ws + off);
  off += (size_t)B * SEL * 16;
  float* sel_score = (float*)(ws + off);
  off += (size_t)B * SEL * 4;
  unsigned long long* mask = (unsigned long long*)(ws + off);
  off += (size_t)B * SEL * NW * 8;
  // total ~27 MB

  // Block geometry for per-batch streaming kernels: A = 261888 = 256*11*93.
  int chunks = (A % (256 * 11) == 0) ? 11 : 1;
  int bpb = (A + 256 * chunks - 1) / (256 * chunks);  // blocks per batch

  hipMemsetAsync(chist, 0, (size_t)B * 256 * 4 * 2, stream);  // chist+fhist
  k_decode<<<dim3(bpb, B), 256, 0, stream>>>((const float4*)anchors,
                                             (const float4*)deltas, scores,
                                             keys, chist, A, chunks);
  k_coarse<<<B, 256, 0, stream>>>(chist, cbArr, cumArr);
  k_fine<<<dim3(bpb, B), 256, 0, stream>>>(keys, cbArr, fhist, A, chunks);
  k_thresh<<<B, 256, 0, stream>>>(fhist, cbArr, cumArr, thresh, cnts);
  k_gather<<<dim3(bpb, B), 256, 0, stream>>>(keys, thresh, cnts, cand_sort, A,
                                             chunks);
  k_fillsel<<<dim3(SEL / 256, B), 256, 0, stream>>>(sel_box, sel_score);
  k_rank<<<dim3(CAP / 256, B), 256, 0, stream>>>(cand_sort, cnts,
                                                 (const float4*)anchors,
                                                 (const float4*)deltas,
                                                 sel_box, sel_score, A);
  k_nmsmask<<<dim3(NW, SEL / 64, B), 64, 0, stream>>>(sel_box, mask);
  k_scanout<<<B, 64, 0, stream>>>(sel_box, sel_score, mask, out);
}

// Round 9
// 424.787 us; speedup vs baseline: 1.1559x; 1.0195x over previous
//
#include <hip/hip_runtime.h>
#include <stdint.h>
#include <math.h>

// RPN proposal filtering: decode -> clip -> validity mask -> stable top-2000
// -> greedy NMS (IoU > 0.7) -> first 1000 kept -> (B, 1000, 5).
//
// R9: R8's scanout fixed two memory pathologies (algorithm unchanged):
// (1) diag column read of row-major [64][32] tile was a 64-way bank conflict
//     (SQ_LDS_BANK_CONFLICT=15872) -> tile row stride padded to 34 u64;
// (2) the OR fold was a dependent ds_read chain paying ~120cyc LDS latency
//     per kept row -> 4-deep batched independent reads (scalar ffs extract,
//     one wait per group). Also: per-chunk ballot finm replaces the
//     per-leader score readlane.

#define IMGF 1024.0f
#define PRE_NMS 2000
#define POST_NMS 1000
#define NMS_THR 0.7f
#define MIN_SZ 16.0f
#define CAP 4096          // candidate buffer per batch
#define SEL 2048          // padded selection stride (>= PRE_NMS)
#define NW (SEL / 64)     // 32 mask words per row
#define CNT_STRIDE 32     // u32s per batch for counters (128 B -> own line)
#define KEY_NEGINF 0x007FFFFFu  // f2key(-inf)
#define MAXCHUNK 12
#define TSTRIDE 34        // u64 per tile row (pad kills diag bank conflict)

// Order-preserving float -> u32 key (all floats incl. -inf totally ordered).
__device__ __forceinline__ uint32_t f2key(float f) {
  uint32_t u = __float_as_uint(f);
  return (u & 0x80000000u) ? ~u : (u | 0x80000000u);
}
__device__ __forceinline__ float key2f(uint32_t k) {
  uint32_t u = (k & 0x80000000u) ? (k & 0x7FFFFFFFu) : ~k;
  return __uint_as_float(u);
}

__device__ __forceinline__ unsigned long long readlane_u64(unsigned long long v,
                                                           int lane) {
  unsigned int lo = __builtin_amdgcn_readlane((unsigned int)v, lane);
  unsigned int hi = __builtin_amdgcn_readlane((unsigned int)(v >> 32), lane);
  return ((unsigned long long)hi << 32) | lo;
}

// Mirrors reference _decode + clip, fp32.
__device__ __forceinline__ float4 decode_clip(float4 anc, float4 dlt) {
  float aw = anc.z - anc.x;
  float ah = anc.w - anc.y;
  float ax = anc.x + 0.5f * aw;
  float ay = anc.y + 0.5f * ah;
  float dw = fminf(dlt.z, 4.0f);
  float dh = fminf(dlt.w, 4.0f);
  float px = dlt.x * aw + ax;
  float py = dlt.y * ah + ay;
  float pw = expf(dw) * aw;
  float ph = expf(dh) * ah;
  float x1 = px - 0.5f * pw, y1 = py - 0.5f * ph;
  float x2 = px + 0.5f * pw, y2 = py + 0.5f * ph;
  x1 = fminf(fmaxf(x1, 0.0f), IMGF);
  y1 = fminf(fmaxf(y1, 0.0f), IMGF);
  x2 = fminf(fmaxf(x2, 0.0f), IMGF);
  y2 = fminf(fmaxf(y2, 0.0f), IMGF);
  return make_float4(x1, y1, x2, y2);
}

// K1: decode -> masked-score key; per-block LDS coarse hist of key>>24
// (finite keys only), ballot-match wave aggregation, one aggregated global
// flush per block. grid = (bpb, B).
__global__ void k_decode(const float4* __restrict__ anchors,
                         const float4* __restrict__ deltas,
                         const float* __restrict__ scores,
                         uint32_t* __restrict__ keys,
                         uint32_t* __restrict__ chist,
                         int A, int chunks) {
  int b = blockIdx.y;
  int t = threadIdx.x;  // 256
  int lane = t & 63;
  __shared__ uint32_t shist[256];
  shist[t] = 0;
  __syncthreads();
  int base_a = blockIdx.x * (chunks * 256);
  for (int c = 0; c < chunks; c++) {
    int a = base_a + c * 256 + t;
    bool inb = a < A;
    int ac = inb ? a : (A - 1);
    size_t i = (size_t)b * A + ac;
    float4 box = decode_clip(anchors[ac], deltas[i]);
    bool valid = (box.z - box.x >= MIN_SZ) && (box.w - box.y >= MIN_SZ);
    float ms = valid ? scores[i] : -INFINITY;
    uint32_t k = f2key(ms);
    if (inb) keys[i] = k;
    uint32_t bucket = k >> 24;
    bool fin = inb && (k != KEY_NEGINF);
    // lanes with equal bucket -> one LDS atomic by the leader
    unsigned long long match = __ballot(fin);
#pragma unroll
    for (int bit = 0; bit < 8; bit++) {
      bool hb = (bucket >> bit) & 1;
      unsigned long long bb = __ballot(hb && fin);
      match &= hb ? bb : ~bb;
    }
    if (fin && (__ffsll((long long)match) - 1 == lane))
      atomicAdd(&shist[bucket], (uint32_t)__popcll(match));
  }
  __syncthreads();
  uint32_t v = shist[t];
  if (v) atomicAdd(&chist[b * 256 + t], v);
}

// K2: pick coarse bucket cb s.t. countAbove(cb) < PRE_NMS <= countAbove(cb)+chist[cb].
__global__ void k_coarse(const uint32_t* __restrict__ chist,
                         int* __restrict__ cbArr,
                         uint32_t* __restrict__ cumArr) {
  int b = blockIdx.x;
  int t = threadIdx.x;  // 256
  __shared__ uint32_t sA[256];
  sA[t] = chist[b * 256 + t];
  for (int d = 1; d < 256; d <<= 1) {  // inclusive suffix scan
    __syncthreads();
    uint32_t v = sA[t] + ((t + d < 256) ? sA[t + d] : 0u);
    __syncthreads();
    sA[t] = v;
  }
  __syncthreads();
  if (t == 0 && sA[0] < PRE_NMS) {  // degenerate: < PRE_NMS finite entries
    cbArr[b] = -1;
    cumArr[b] = 0;
  }
  uint32_t nxt = (t < 255) ? sA[t + 1] : 0u;
  if (sA[t] >= PRE_NMS && nxt < PRE_NMS) {
    cbArr[b] = t;
    cumArr[b] = nxt;  // count strictly above coarse bucket t
  }
}

// K3: fine hist of key bits[23:16] for elements whose coarse bucket == cb[b].
__global__ void k_fine(const uint32_t* __restrict__ keys,
                       const int* __restrict__ cbArr,
                       uint32_t* __restrict__ fhist,
                       int A, int chunks) {
  int b = blockIdx.y;
  int t = threadIdx.x;  // 256
  int cb = cbArr[b];
  if (cb < 0) return;
  __shared__ uint32_t shist[256];
  shist[t] = 0;
  __syncthreads();
  int base_a = blockIdx.x * (chunks * 256);
  uint32_t cbu = (uint32_t)cb;
  for (int c = 0; c < chunks; c++) {
    int a = base_a + c * 256 + t;
    if (a >= A) break;
    uint32_t k = keys[(size_t)b * A + a];
    if ((k >> 24) == cbu && k != KEY_NEGINF)
      atomicAdd(&shist[(k >> 16) & 0xFFu], 1u);
  }
  __syncthreads();
  uint32_t v = shist[t];
  if (v) atomicAdd(&fhist[b * 256 + t], v);
}

// K4: final 16-bit threshold beta = (cb<<8)|d:
// count(key>>16 > beta) < PRE_NMS <= count(key>>16 >= beta), finite keys only.
__global__ void k_thresh(const uint32_t* __restrict__ fhist,
                         const int* __restrict__ cbArr,
                         const uint32_t* __restrict__ cumArr,
                         uint32_t* __restrict__ thresh,
                         uint32_t* __restrict__ cnts) {
  int b = blockIdx.x;
  int t = threadIdx.x;  // 256
  __shared__ uint32_t sA[256];
  if (t < 2) cnts[b * CNT_STRIDE + t] = 0;
  int cb = cbArr[b];
  if (cb < 0) {
    if (t == 0) thresh[b] = 0u;
    return;
  }
  uint32_t cumAbove = cumArr[b];
  sA[t] = fhist[b * 256 + t];
  for (int d = 1; d < 256; d <<= 1) {
    __syncthreads();
    uint32_t v = sA[t] + ((t + d < 256) ? sA[t + d] : 0u);
    __syncthreads();
    sA[t] = v;
  }
  __syncthreads();
  uint32_t nxt = (t < 255) ? sA[t + 1] : 0u;
  if (cumAbove + sA[t] >= PRE_NMS && cumAbove + nxt < PRE_NMS)
    thresh[b] = (uint32_t)((cb << 8) | t);
}

// K5: gather candidate KEYS ONLY (8B each), block-aggregated atomics: one
// atomicAdd per category per block. Strictly-above fills [0, c1); ties fill
// from CAP-1 downward; overflow ties dropped (only above 2096 ties/batch).
__global__ void k_gather(const uint32_t* __restrict__ keys,
                         const uint32_t* __restrict__ thresh,
                         uint32_t* __restrict__ cnts,
                         unsigned long long* __restrict__ cand_sort,
                         int A, int chunks) {
  int b = blockIdx.y;
  int t = threadIdx.x;  // 256
  int lane = t & 63;
  int w = t >> 6;  // wave 0..3
  __shared__ unsigned long long s_mA[MAXCHUNK * 4], s_mT[MAXCHUNK * 4];
  __shared__ uint32_t s_offA[MAXCHUNK * 4], s_offT[MAXCHUNK * 4];
  __shared__ uint32_t s_cA[MAXCHUNK * 4], s_cT[MAXCHUNK * 4];
  __shared__ uint32_t s_baseA, s_baseT;
  uint32_t beta = thresh[b];
  uint32_t kreg[MAXCHUNK];
  int base_a = blockIdx.x * (chunks * 256);
  for (int c = 0; c < chunks; c++) {
    int a = base_a + c * 256 + t;
    bool inb = a < A;
    uint32_t k = inb ? keys[(size_t)b * A + a] : KEY_NEGINF;
    kreg[c] = k;
    uint32_t bk = k >> 16;
    bool fin = (k != KEY_NEGINF);
    unsigned long long mA = __ballot(fin && (bk > beta));
    unsigned long long mT = __ballot(fin && (bk == beta));
    if (lane == 0) {
      s_mA[c * 4 + w] = mA;
      s_mT[c * 4 + w] = mT;
    }
  }
  __syncthreads();
  if (t < chunks * 4) {
    s_cA[t] = (uint32_t)__popcll(s_mA[t]);
    s_cT[t] = (uint32_t)__popcll(s_mT[t]);
  }
  __syncthreads();
  if (t == 0) {  // serial scan over <=44 entries, then ONE atomic per category
    uint32_t accA = 0, accT = 0;
    for (int id = 0; id < chunks * 4; id++) {
      s_offA[id] = accA;
      accA += s_cA[id];
      s_offT[id] = accT;
      accT += s_cT[id];
    }
    s_baseA = accA ? atomicAdd(&cnts[b * CNT_STRIDE + 0], accA) : 0u;
    s_baseT = accT ? atomicAdd(&cnts[b * CNT_STRIDE + 1], accT) : 0u;
  }
  __syncthreads();
  uint32_t baseA = s_baseA, baseT = s_baseT;
  unsigned long long lower = ((unsigned long long)1 << lane) - 1;
  for (int c = 0; c < chunks; c++) {
    int id = c * 4 + w;
    unsigned long long mA = s_mA[id], mT = s_mT[id];
    bool above = (mA >> lane) & 1;
    bool tie = (mT >> lane) & 1;
    if (!(above || tie)) continue;
    int pos;
    if (above) {
      pos = (int)(baseA + s_offA[id] + (uint32_t)__popcll(mA & lower));
      if (pos >= PRE_NMS) continue;  // defensive; cannot happen
    } else {
      pos = CAP - 1 - (int)(baseT + s_offT[id] + (uint32_t)__popcll(mT & lower));
      if (pos < PRE_NMS) continue;  // drop overflow ties
    }
    int a = base_a + c * 256 + t;
    // sort key: (score_key desc, anchor index asc) via descending u64 order
    cand_sort[(size_t)b * CAP + pos] =
        ((unsigned long long)kreg[c] << 32) | (uint32_t)(~(uint32_t)a);
  }
}

// K6a: default-fill selection (pads for degenerate batches; overwritten by
// k_rank for every live rank < SEL). grid = (SEL/256, B).
__global__ void k_fillsel(float4* __restrict__ sel_box,
                          float* __restrict__ sel_score) {
  int b = blockIdx.y;
  int r = blockIdx.x * 256 + threadIdx.x;
  sel_score[(size_t)b * SEL + r] = -INFINITY;
  sel_box[(size_t)b * SEL + r] = make_float4(0.0f, 0.0f, 0.0f, 0.0f);
}

// K6b: enumeration sort. Keys are strictly distinct ((score_key, ~anchor)),
// so rank = #{keys > mine} is the exact descending-sorted position. Each
// thread owns one slot, streams the batch's live slots through LDS broadcast
// tiles, and (if rank < SEL) decodes its box from the embedded anchor index.
// grid = (CAP/256, B).
__global__ void k_rank(const unsigned long long* __restrict__ cand_sort,
                       const uint32_t* __restrict__ cnts,
                       const float4* __restrict__ anchors,
                       const float4* __restrict__ deltas,
                       float4* __restrict__ sel_box,
                       float* __restrict__ sel_score, int A) {
  int b = blockIdx.y;
  int t = threadIdx.x;  // 256
  uint32_t c1 = cnts[b * CNT_STRIDE + 0];
  if (c1 > PRE_NMS) c1 = PRE_NMS;
  uint32_t c2 = cnts[b * CNT_STRIDE + 1];
  if (c2 > CAP - PRE_NMS) c2 = CAP - PRE_NMS;
  int loTie = CAP - (int)c2;
  int bs = blockIdx.x * 256;
  if (bs >= (int)c1 && bs + 256 <= loTie) return;  // block fully in dead gap
  int s = bs + t;
  bool live = (s < (int)c1) || (s >= loTie);
  unsigned long long myKey = live ? cand_sort[(size_t)b * CAP + s] : 0ull;
  __shared__ unsigned long long tile[256];
  int rank = 0;
  for (int ts = 0; ts < CAP; ts += 256) {  // tile-skip is block-uniform
    if (ts >= (int)c1 && ts + 256 <= loTie) continue;
    int idx = ts + t;
    bool lv = (idx < (int)c1) || (idx >= loTie);
    __syncthreads();
    tile[t] = lv ? cand_sort[(size_t)b * CAP + idx] : 0ull;
    __syncthreads();
    if (live) {
#pragma unroll 8
      for (int j = 0; j < 256; j++) rank += (tile[j] > myKey) ? 1 : 0;
    }
  }
  if (live && rank < SEL) {
    uint32_t a = ~((uint32_t)myKey);
    float4 box = decode_clip(anchors[a], deltas[(size_t)b * A + a]);
    sel_score[(size_t)b * SEL + rank] = key2f((uint32_t)(myKey >> 32));
    sel_box[(size_t)b * SEL + rank] = box;
  }
}

// K7: suppression bitmask. mask[b][i][jb] bit jj set iff j = jb*64+jj > i,
// j < PRE_NMS, IoU(box_i, box_j) > NMS_THR. Rows in [PRE_NMS, SEL) zeroed
// so k_scanout never reads unwritten workspace.
__global__ void k_nmsmask(const float4* __restrict__ sel_box,
                          unsigned long long* __restrict__ mask) {
  int jb = blockIdx.x;  // col block
  int ib = blockIdx.y;  // row block
  int b = blockIdx.z;
  int t = threadIdx.x;  // 64
  int i = ib * 64 + t;
  if (jb < ib) {  // uniform per block; entire col tile is <= all rows
    mask[((size_t)b * SEL + i) * NW + jb] = 0ull;
    return;
  }
  __shared__ float4 cb[64];
  __shared__ float careb[64];
  int j0 = jb * 64;
  float4 cbx = sel_box[(size_t)b * SEL + j0 + t];
  cb[t] = cbx;
  careb[t] = (cbx.z - cbx.x) * (cbx.w - cbx.y);
  __syncthreads();
  if (i >= PRE_NMS) {  // pad rows: write zeros, never leave stale poison
    mask[((size_t)b * SEL + i) * NW + jb] = 0ull;
    return;
  }
  float4 a = sel_box[(size_t)b * SEL + i];
  float area_a = (a.z - a.x) * (a.w - a.y);
  unsigned long long bits = 0ull;
  int jmax = min(64, PRE_NMS - j0);
  for (int jj = 0; jj < jmax; jj++) {
    int j = j0 + jj;
    if (j <= i) continue;
    float4 bb = cb[jj];
    float ltx = fmaxf(a.x, bb.x), lty = fmaxf(a.y, bb.y);
    float rbx = fminf(a.z, bb.z), rby = fminf(a.w, bb.w);
    float w = fmaxf(rbx - ltx, 0.0f), hgt = fmaxf(rby - lty, 0.0f);
    float inter = w * hgt;
    float iou = inter / (area_a + careb[jj] - inter + 1e-6f);
    if (iou > NMS_THR) bits |= (1ull << jj);
  }
  mask[((size_t)b * SEL + i) * NW + jb] = bits;
}

// K8 (R9): one wave per batch; padded LDS tile double buffer (stride 34 u64).
// Per chunk: resolve keep-set from register diag (ffs/readlane, scalar finm
// ballot for the finite test); OR-fold kept rows with 4-deep batched
// independent ds_read_b64 groups (amortizes ~120cyc LDS latency); staging
// prefetched into 16 ulonglong2 regs at top, committed at bottom.
__global__ void __launch_bounds__(64, 1) k_scanout(
    const float4* __restrict__ sel_box,
    const float* __restrict__ sel_score,
    const unsigned long long* __restrict__ mask,
    float* __restrict__ out) {
  int b = blockIdx.x;
  int t = threadIdx.x;  // 64 = 1 wave
  int tw = t & 31;
  __shared__ unsigned long long sTile[2][64 * TSTRIDE];  // 2 x 17 KB
  __shared__ uint32_t keptList[POST_NMS];
  const unsigned long long* mbase = mask + (size_t)b * SEL * NW;
  unsigned long long removed = 0ull;  // lane t holds word tw (dup per half)
  int kc = 0;
  const int NCH = (PRE_NMS + 63) / 64;  // 32; diag word index == chunk < NW

  typedef ulonglong2 ull2;
  // lane t, q -> word pair (row r = 4q + (t>>4), col c = 2*(t&15)) of tile;
  // padded ull2 index = r*17 + (t&15).
  int r_l = t >> 4;
  int ch_l = t & 15;
  {  // prime tile 0
    const ull2* g0 = (const ull2*)mbase;
    ull2* d0 = (ull2*)sTile[0];
#pragma unroll
    for (int q = 0; q < 16; q++)
      d0[(4 * q + r_l) * 17 + ch_l] = g0[q * 64 + t];
  }
  uint32_t s_cur = __float_as_uint(sel_score[(size_t)b * SEL + t]);

  for (int chunk = 0; chunk < NCH; chunk++) {
    int buf = chunk & 1;
    ull2 stg[16];
    uint32_t s_nxt = 0;
    bool hasNext = (chunk + 1 < NCH);
    if (hasNext) {  // issue next-tile global loads now, commit at bottom
      const ull2* gn = (const ull2*)(mbase + (size_t)(chunk + 1) * 64 * NW);
#pragma unroll
      for (int q = 0; q < 16; q++) stg[q] = gn[q * 64 + t];
      s_nxt = __float_as_uint(sel_score[(size_t)b * SEL + (chunk + 1) * 64 + t]);
    }
    unsigned long long finm = __ballot(s_cur != 0xFF800000u);  // finite rows
    // diag: lane r = row r's word `chunk` (in-chunk forward suppression)
    unsigned long long diag = sTile[buf][t * TSTRIDE + chunk];
    int rmax = PRE_NMS - chunk * 64;
    if (rmax > 64) rmax = 64;
    unsigned long long alive = ~readlane_u64(removed, chunk);
    if (rmax < 64) alive &= (((unsigned long long)1 << rmax) - 1);
    unsigned long long keepm = 0ull;
    while (alive) {
      int r = __ffsll((long long)alive) - 1;
      unsigned long long rb = (unsigned long long)1 << r;
      keepm |= rb;
      alive &= ~rb;
      if ((finm >> r) & 1ull) {  // finite score: counted & output
        if (t == 0) keptList[kc] = (uint32_t)(chunk * 64 + r);
        kc++;
        if (kc == POST_NMS) goto writeout;
      }
      alive &= ~readlane_u64(diag, r);  // forward in-chunk suppression
    }
    {  // OR phase: 4-deep batched independent LDS reads per group
      unsigned long long partial = 0ull;
      unsigned long long km = keepm;
      const unsigned long long* sT = &sTile[buf][0];
      while (km) {
        int r0 = __ffsll((long long)km) - 1;
        km &= km - 1;
        int r1 = r0, r2 = r0, r3 = r0;
        if (km) { r1 = __ffsll((long long)km) - 1; km &= km - 1; }
        if (km) { r2 = __ffsll((long long)km) - 1; km &= km - 1; }
        if (km) { r3 = __ffsll((long long)km) - 1; km &= km - 1; }
        unsigned long long w0 = sT[r0 * TSTRIDE + tw];
        unsigned long long w1 = sT[r1 * TSTRIDE + tw];
        unsigned long long w2 = sT[r2 * TSTRIDE + tw];
        unsigned long long w3 = sT[r3 * TSTRIDE + tw];
        partial |= (w0 | w1) | (w2 | w3);
      }
      removed |=
          partial | (unsigned long long)__shfl_xor((long long)partial, 32);
    }
    if (hasNext) {  // commit prefetched tile to the other buffer
      ull2* dn = (ull2*)sTile[buf ^ 1];
#pragma unroll
      for (int q = 0; q < 16; q++)
        dn[(4 * q + r_l) * 17 + ch_l] = stg[q];
      s_cur = s_nxt;
    }
  }
writeout:
  __syncthreads();
  for (int r = t; r < POST_NMS; r += 64) {
    float4 bx = make_float4(0.0f, 0.0f, 0.0f, 0.0f);
    float sc = 0.0f;
    if (r < kc) {
      int i = (int)keptList[r];
      bx = sel_box[(size_t)b * SEL + i];
      sc = sel_score[(size_t)b * SEL + i];
    }
    float* o = out + ((size_t)b * POST_NMS + r) * 5;
    o[0] = bx.x;
    o[1] = bx.y;
    o[2] = bx.z;
    o[3] = bx.w;
    o[4] = sc;
  }
}

extern "C" void kernel_launch(void* const* d_in, const int* in_sizes, int n_in,
                              void* d_out, int out_size, void* d_ws, size_t ws_size,
                              hipStream_t stream) {
  const float* anchors = (const float*)d_in[0];  // (A, 4)
  const float* deltas = (const float*)d_in[1];   // (B, A, 4)
  const float* scores = (const float*)d_in[2];   // (B, A)
  int A = in_sizes[0] / 4;
  int BA = in_sizes[2];
  int B = BA / A;
  float* out = (float*)d_out;

  char* ws = (char*)d_ws;
  size_t off = 0;
  uint32_t* keys = (uint32_t*)(ws + off);
  off += (size_t)BA * 4;
  uint32_t* chist = (uint32_t*)(ws + off);
  off += (size_t)B * 256 * 4;
  uint32_t* fhist = (uint32_t*)(ws + off);
  off += (size_t)B * 256 * 4;
  int* cbArr = (int*)(ws + off);
  off += (size_t)B * 4;
  uint32_t* cumArr = (uint32_t*)(ws + off);
  off += (size_t)B * 4;
  uint32_t* thresh = (uint32_t*)(ws + off);
  off += (size_t)B * 4;
  off = (off + 127) & ~(size_t)127;
  uint32_t* cnts = (uint32_t*)(ws + off);
  off += (size_t)B * CNT_STRIDE * 4;
  off = (off + 15) & ~(size_t)15;
  unsigned long long* cand_sort = (unsigned long long*)(ws + off);
  off += (size_t)B * CAP * 8;
  float4* sel_box = (float4*)(ws + off);
  off += (size_t)B * SEL * 16;
  float* sel_score = (float*)(ws + off);
  off += (size_t)B * SEL * 4;
  unsigned long long* mask = (unsigned long long*)(ws + off);
  off += (size_t)B * SEL * NW * 8;
  // total ~27 MB

  // Block geometry for per-batch streaming kernels: A = 261888 = 256*11*93.
  int chunks = (A % (256 * 11) == 0) ? 11 : 1;
  int bpb = (A + 256 * chunks - 1) / (256 * chunks);  // blocks per batch

  hipMemsetAsync(chist, 0, (size_t)B * 256 * 4 * 2, stream);  // chist+fhist
  k_decode<<<dim3(bpb, B), 256, 0, stream>>>((const float4*)anchors,
                                             (const float4*)deltas, scores,
                                             keys, chist, A, chunks);
  k_coarse<<<B, 256, 0, stream>>>(chist, cbArr, cumArr);
  k_fine<<<dim3(bpb, B), 256, 0, stream>>>(keys, cbArr, fhist, A, chunks);
  k_thresh<<<B, 256, 0, stream>>>(fhist, cbArr, cumArr, thresh, cnts);
  k_gather<<<dim3(bpb, B), 256, 0, stream>>>(keys, thresh, cnts, cand_sort, A,
                                             chunks);
  k_fillsel<<<dim3(SEL / 256, B), 256, 0, stream>>>(sel_box, sel_score);
  k_rank<<<dim3(CAP / 256, B), 256, 0, stream>>>(cand_sort, cnts,
                                                 (const float4*)anchors,
                                                 (const float4*)deltas,
                                                 sel_box, sel_score, A);
  k_nmsmask<<<dim3(NW, SEL / 64, B), 64, 0, stream>>>(sel_box, mask);
  k_scanout<<<B, 64, 0, stream>>>(sel_box, sel_score, mask, out);
}

// Round 10
// 405.310 us; speedup vs baseline: 1.2114x; 1.0481x over previous
//
#include <hip/hip_runtime.h>
#include <stdint.h>
#include <math.h>

// RPN proposal filtering: decode -> clip -> validity mask -> stable top-2000
// -> greedy NMS (IoU > 0.7) -> first 1000 kept -> (B, 1000, 5).
//
// R10: scanout re-diagnosed. R8/R9's ~13k cyc/chunk matches ~17 serialized
// full-latency loads: the LDS tile commit induced per-load vmcnt waits (zero
// MLP on staging). Fix: no tile at all. Per chunk, only the diagonal word
// (prefetched strided load) + scores (prefetched) + the LEADERS' mask rows
// (256B coalesced each), issued as up to 32 independent register loads with
// ONE vmcnt wait, then tree-ORed into `removed`. No ds_write in the loop.

#define IMGF 1024.0f
#define PRE_NMS 2000
#define POST_NMS 1000
#define NMS_THR 0.7f
#define MIN_SZ 16.0f
#define CAP 4096          // candidate buffer per batch
#define SEL 2048          // padded selection stride (>= PRE_NMS)
#define NW (SEL / 64)     // 32 mask words per row
#define CNT_STRIDE 32     // u32s per batch for counters (128 B -> own line)
#define KEY_NEGINF 0x007FFFFFu  // f2key(-inf)
#define MAXCHUNK 12

// Order-preserving float -> u32 key (all floats incl. -inf totally ordered).
__device__ __forceinline__ uint32_t f2key(float f) {
  uint32_t u = __float_as_uint(f);
  return (u & 0x80000000u) ? ~u : (u | 0x80000000u);
}
__device__ __forceinline__ float key2f(uint32_t k) {
  uint32_t u = (k & 0x80000000u) ? (k & 0x7FFFFFFFu) : ~k;
  return __uint_as_float(u);
}

__device__ __forceinline__ unsigned long long readlane_u64(unsigned long long v,
                                                           int lane) {
  unsigned int lo = __builtin_amdgcn_readlane((unsigned int)v, lane);
  unsigned int hi = __builtin_amdgcn_readlane((unsigned int)(v >> 32), lane);
  return ((unsigned long long)hi << 32) | lo;
}

// Mirrors reference _decode + clip, fp32.
__device__ __forceinline__ float4 decode_clip(float4 anc, float4 dlt) {
  float aw = anc.z - anc.x;
  float ah = anc.w - anc.y;
  float ax = anc.x + 0.5f * aw;
  float ay = anc.y + 0.5f * ah;
  float dw = fminf(dlt.z, 4.0f);
  float dh = fminf(dlt.w, 4.0f);
  float px = dlt.x * aw + ax;
  float py = dlt.y * ah + ay;
  float pw = expf(dw) * aw;
  float ph = expf(dh) * ah;
  float x1 = px - 0.5f * pw, y1 = py - 0.5f * ph;
  float x2 = px + 0.5f * pw, y2 = py + 0.5f * ph;
  x1 = fminf(fmaxf(x1, 0.0f), IMGF);
  y1 = fminf(fmaxf(y1, 0.0f), IMGF);
  x2 = fminf(fmaxf(x2, 0.0f), IMGF);
  y2 = fminf(fmaxf(y2, 0.0f), IMGF);
  return make_float4(x1, y1, x2, y2);
}

// K1: decode -> masked-score key; per-block LDS coarse hist of key>>24
// (finite keys only), ballot-match wave aggregation, one aggregated global
// flush per block. grid = (bpb, B).
__global__ void k_decode(const float4* __restrict__ anchors,
                         const float4* __restrict__ deltas,
                         const float* __restrict__ scores,
                         uint32_t* __restrict__ keys,
                         uint32_t* __restrict__ chist,
                         int A, int chunks) {
  int b = blockIdx.y;
  int t = threadIdx.x;  // 256
  int lane = t & 63;
  __shared__ uint32_t shist[256];
  shist[t] = 0;
  __syncthreads();
  int base_a = blockIdx.x * (chunks * 256);
  for (int c = 0; c < chunks; c++) {
    int a = base_a + c * 256 + t;
    bool inb = a < A;
    int ac = inb ? a : (A - 1);
    size_t i = (size_t)b * A + ac;
    float4 box = decode_clip(anchors[ac], deltas[i]);
    bool valid = (box.z - box.x >= MIN_SZ) && (box.w - box.y >= MIN_SZ);
    float ms = valid ? scores[i] : -INFINITY;
    uint32_t k = f2key(ms);
    if (inb) keys[i] = k;
    uint32_t bucket = k >> 24;
    bool fin = inb && (k != KEY_NEGINF);
    // lanes with equal bucket -> one LDS atomic by the leader
    unsigned long long match = __ballot(fin);
#pragma unroll
    for (int bit = 0; bit < 8; bit++) {
      bool hb = (bucket >> bit) & 1;
      unsigned long long bb = __ballot(hb && fin);
      match &= hb ? bb : ~bb;
    }
    if (fin && (__ffsll((long long)match) - 1 == lane))
      atomicAdd(&shist[bucket], (uint32_t)__popcll(match));
  }
  __syncthreads();
  uint32_t v = shist[t];
  if (v) atomicAdd(&chist[b * 256 + t], v);
}

// K2: pick coarse bucket cb s.t. countAbove(cb) < PRE_NMS <= countAbove(cb)+chist[cb].
__global__ void k_coarse(const uint32_t* __restrict__ chist,
                         int* __restrict__ cbArr,
                         uint32_t* __restrict__ cumArr) {
  int b = blockIdx.x;
  int t = threadIdx.x;  // 256
  __shared__ uint32_t sA[256];
  sA[t] = chist[b * 256 + t];
  for (int d = 1; d < 256; d <<= 1) {  // inclusive suffix scan
    __syncthreads();
    uint32_t v = sA[t] + ((t + d < 256) ? sA[t + d] : 0u);
    __syncthreads();
    sA[t] = v;
  }
  __syncthreads();
  if (t == 0 && sA[0] < PRE_NMS) {  // degenerate: < PRE_NMS finite entries
    cbArr[b] = -1;
    cumArr[b] = 0;
  }
  uint32_t nxt = (t < 255) ? sA[t + 1] : 0u;
  if (sA[t] >= PRE_NMS && nxt < PRE_NMS) {
    cbArr[b] = t;
    cumArr[b] = nxt;  // count strictly above coarse bucket t
  }
}

// K3: fine hist of key bits[23:16] for elements whose coarse bucket == cb[b].
__global__ void k_fine(const uint32_t* __restrict__ keys,
                       const int* __restrict__ cbArr,
                       uint32_t* __restrict__ fhist,
                       int A, int chunks) {
  int b = blockIdx.y;
  int t = threadIdx.x;  // 256
  int cb = cbArr[b];
  if (cb < 0) return;
  __shared__ uint32_t shist[256];
  shist[t] = 0;
  __syncthreads();
  int base_a = blockIdx.x * (chunks * 256);
  uint32_t cbu = (uint32_t)cb;
  for (int c = 0; c < chunks; c++) {
    int a = base_a + c * 256 + t;
    if (a >= A) break;
    uint32_t k = keys[(size_t)b * A + a];
    if ((k >> 24) == cbu && k != KEY_NEGINF)
      atomicAdd(&shist[(k >> 16) & 0xFFu], 1u);
  }
  __syncthreads();
  uint32_t v = shist[t];
  if (v) atomicAdd(&fhist[b * 256 + t], v);
}

// K4: final 16-bit threshold beta = (cb<<8)|d:
// count(key>>16 > beta) < PRE_NMS <= count(key>>16 >= beta), finite keys only.
__global__ void k_thresh(const uint32_t* __restrict__ fhist,
                         const int* __restrict__ cbArr,
                         const uint32_t* __restrict__ cumArr,
                         uint32_t* __restrict__ thresh,
                         uint32_t* __restrict__ cnts) {
  int b = blockIdx.x;
  int t = threadIdx.x;  // 256
  __shared__ uint32_t sA[256];
  if (t < 2) cnts[b * CNT_STRIDE + t] = 0;
  int cb = cbArr[b];
  if (cb < 0) {
    if (t == 0) thresh[b] = 0u;
    return;
  }
  uint32_t cumAbove = cumArr[b];
  sA[t] = fhist[b * 256 + t];
  for (int d = 1; d < 256; d <<= 1) {
    __syncthreads();
    uint32_t v = sA[t] + ((t + d < 256) ? sA[t + d] : 0u);
    __syncthreads();
    sA[t] = v;
  }
  __syncthreads();
  uint32_t nxt = (t < 255) ? sA[t + 1] : 0u;
  if (cumAbove + sA[t] >= PRE_NMS && cumAbove + nxt < PRE_NMS)
    thresh[b] = (uint32_t)((cb << 8) | t);
}

// K5: gather candidate KEYS ONLY (8B each), block-aggregated atomics: one
// atomicAdd per category per block. Strictly-above fills [0, c1); ties fill
// from CAP-1 downward; overflow ties dropped (only above 2096 ties/batch).
__global__ void k_gather(const uint32_t* __restrict__ keys,
                         const uint32_t* __restrict__ thresh,
                         uint32_t* __restrict__ cnts,
                         unsigned long long* __restrict__ cand_sort,
                         int A, int chunks) {
  int b = blockIdx.y;
  int t = threadIdx.x;  // 256
  int lane = t & 63;
  int w = t >> 6;  // wave 0..3
  __shared__ unsigned long long s_mA[MAXCHUNK * 4], s_mT[MAXCHUNK * 4];
  __shared__ uint32_t s_offA[MAXCHUNK * 4], s_offT[MAXCHUNK * 4];
  __shared__ uint32_t s_cA[MAXCHUNK * 4], s_cT[MAXCHUNK * 4];
  __shared__ uint32_t s_baseA, s_baseT;
  uint32_t beta = thresh[b];
  uint32_t kreg[MAXCHUNK];
  int base_a = blockIdx.x * (chunks * 256);
  for (int c = 0; c < chunks; c++) {
    int a = base_a + c * 256 + t;
    bool inb = a < A;
    uint32_t k = inb ? keys[(size_t)b * A + a] : KEY_NEGINF;
    kreg[c] = k;
    uint32_t bk = k >> 16;
    bool fin = (k != KEY_NEGINF);
    unsigned long long mA = __ballot(fin && (bk > beta));
    unsigned long long mT = __ballot(fin && (bk == beta));
    if (lane == 0) {
      s_mA[c * 4 + w] = mA;
      s_mT[c * 4 + w] = mT;
    }
  }
  __syncthreads();
  if (t < chunks * 4) {
    s_cA[t] = (uint32_t)__popcll(s_mA[t]);
    s_cT[t] = (uint32_t)__popcll(s_mT[t]);
  }
  __syncthreads();
  if (t == 0) {  // serial scan over <=44 entries, then ONE atomic per category
    uint32_t accA = 0, accT = 0;
    for (int id = 0; id < chunks * 4; id++) {
      s_offA[id] = accA;
      accA += s_cA[id];
      s_offT[id] = accT;
      accT += s_cT[id];
    }
    s_baseA = accA ? atomicAdd(&cnts[b * CNT_STRIDE + 0], accA) : 0u;
    s_baseT = accT ? atomicAdd(&cnts[b * CNT_STRIDE + 1], accT) : 0u;
  }
  __syncthreads();
  uint32_t baseA = s_baseA, baseT = s_baseT;
  unsigned long long lower = ((unsigned long long)1 << lane) - 1;
  for (int c = 0; c < chunks; c++) {
    int id = c * 4 + w;
    unsigned long long mA = s_mA[id], mT = s_mT[id];
    bool above = (mA >> lane) & 1;
    bool tie = (mT >> lane) & 1;
    if (!(above || tie)) continue;
    int pos;
    if (above) {
      pos = (int)(baseA + s_offA[id] + (uint32_t)__popcll(mA & lower));
      if (pos >= PRE_NMS) continue;  // defensive; cannot happen
    } else {
      pos = CAP - 1 - (int)(baseT + s_offT[id] + (uint32_t)__popcll(mT & lower));
      if (pos < PRE_NMS) continue;  // drop overflow ties
    }
    int a = base_a + c * 256 + t;
    // sort key: (score_key desc, anchor index asc) via descending u64 order
    cand_sort[(size_t)b * CAP + pos] =
        ((unsigned long long)kreg[c] << 32) | (uint32_t)(~(uint32_t)a);
  }
}

// K6a: default-fill selection (pads for degenerate batches; overwritten by
// k_rank for every live rank < SEL). grid = (SEL/256, B).
__global__ void k_fillsel(float4* __restrict__ sel_box,
                          float* __restrict__ sel_score) {
  int b = blockIdx.y;
  int r = blockIdx.x * 256 + threadIdx.x;
  sel_score[(size_t)b * SEL + r] = -INFINITY;
  sel_box[(size_t)b * SEL + r] = make_float4(0.0f, 0.0f, 0.0f, 0.0f);
}

// K6b: enumeration sort. Keys are strictly distinct ((score_key, ~anchor)),
// so rank = #{keys > mine} is the exact descending-sorted position. Each
// thread owns one slot, streams the batch's live slots through LDS broadcast
// tiles, and (if rank < SEL) decodes its box from the embedded anchor index.
// grid = (CAP/256, B).
__global__ void k_rank(const unsigned long long* __restrict__ cand_sort,
                       const uint32_t* __restrict__ cnts,
                       const float4* __restrict__ anchors,
                       const float4* __restrict__ deltas,
                       float4* __restrict__ sel_box,
                       float* __restrict__ sel_score, int A) {
  int b = blockIdx.y;
  int t = threadIdx.x;  // 256
  uint32_t c1 = cnts[b * CNT_STRIDE + 0];
  if (c1 > PRE_NMS) c1 = PRE_NMS;
  uint32_t c2 = cnts[b * CNT_STRIDE + 1];
  if (c2 > CAP - PRE_NMS) c2 = CAP - PRE_NMS;
  int loTie = CAP - (int)c2;
  int bs = blockIdx.x * 256;
  if (bs >= (int)c1 && bs + 256 <= loTie) return;  // block fully in dead gap
  int s = bs + t;
  bool live = (s < (int)c1) || (s >= loTie);
  unsigned long long myKey = live ? cand_sort[(size_t)b * CAP + s] : 0ull;
  __shared__ unsigned long long tile[256];
  int rank = 0;
  for (int ts = 0; ts < CAP; ts += 256) {  // tile-skip is block-uniform
    if (ts >= (int)c1 && ts + 256 <= loTie) continue;
    int idx = ts + t;
    bool lv = (idx < (int)c1) || (idx >= loTie);
    __syncthreads();
    tile[t] = lv ? cand_sort[(size_t)b * CAP + idx] : 0ull;
    __syncthreads();
    if (live) {
#pragma unroll 8
      for (int j = 0; j < 256; j++) rank += (tile[j] > myKey) ? 1 : 0;
    }
  }
  if (live && rank < SEL) {
    uint32_t a = ~((uint32_t)myKey);
    float4 box = decode_clip(anchors[a], deltas[(size_t)b * A + a]);
    sel_score[(size_t)b * SEL + rank] = key2f((uint32_t)(myKey >> 32));
    sel_box[(size_t)b * SEL + rank] = box;
  }
}

// K7: suppression bitmask. mask[b][i][jb] bit jj set iff j = jb*64+jj > i,
// j < PRE_NMS, IoU(box_i, box_j) > NMS_THR. Rows in [PRE_NMS, SEL) zeroed
// so k_scanout never reads unwritten workspace.
__global__ void k_nmsmask(const float4* __restrict__ sel_box,
                          unsigned long long* __restrict__ mask) {
  int jb = blockIdx.x;  // col block
  int ib = blockIdx.y;  // row block
  int b = blockIdx.z;
  int t = threadIdx.x;  // 64
  int i = ib * 64 + t;
  if (jb < ib) {  // uniform per block; entire col tile is <= all rows
    mask[((size_t)b * SEL + i) * NW + jb] = 0ull;
    return;
  }
  __shared__ float4 cb[64];
  __shared__ float careb[64];
  int j0 = jb * 64;
  float4 cbx = sel_box[(size_t)b * SEL + j0 + t];
  cb[t] = cbx;
  careb[t] = (cbx.z - cbx.x) * (cbx.w - cbx.y);
  __syncthreads();
  if (i >= PRE_NMS) {  // pad rows: write zeros, never leave stale poison
    mask[((size_t)b * SEL + i) * NW + jb] = 0ull;
    return;
  }
  float4 a = sel_box[(size_t)b * SEL + i];
  float area_a = (a.z - a.x) * (a.w - a.y);
  unsigned long long bits = 0ull;
  int jmax = min(64, PRE_NMS - j0);
  for (int jj = 0; jj < jmax; jj++) {
    int j = j0 + jj;
    if (j <= i) continue;
    float4 bb = cb[jj];
    float ltx = fmaxf(a.x, bb.x), lty = fmaxf(a.y, bb.y);
    float rbx = fminf(a.z, bb.z), rby = fminf(a.w, bb.w);
    float w = fmaxf(rbx - ltx, 0.0f), hgt = fmaxf(rby - lty, 0.0f);
    float inter = w * hgt;
    float iou = inter / (area_a + careb[jj] - inter + 1e-6f);
    if (iou > NMS_THR) bits |= (1ull << jj);
  }
  mask[((size_t)b * SEL + i) * NW + jb] = bits;
}

// K8 (R10): one wave per batch, NO LDS tile. Per chunk: diag word + scores
// prefetched one chunk ahead (registers); resolve keep-set via scalar
// ffs/readlane; fold = up to 32 INDEPENDENT coalesced global loads of the
// leaders' mask rows (lane t reads word t&31 => 256B/row), one vmcnt wait,
// tree-OR into `removed`. Early exit at POST_NMS kept.
__global__ void __launch_bounds__(64, 1) k_scanout(
    const float4* __restrict__ sel_box,
    const float* __restrict__ sel_score,
    const unsigned long long* __restrict__ mask,
    float* __restrict__ out) {
  int b = blockIdx.x;
  int t = threadIdx.x;  // 64 = 1 wave
  int tw = t & 31;
  __shared__ uint32_t keptList[POST_NMS];
  const unsigned long long* mbase = mask + (size_t)b * SEL * NW;
  unsigned long long removed = 0ull;  // lane t holds word tw (dup per half)
  int kc = 0;
  const int NCH = (PRE_NMS + 63) / 64;  // 32

  // prefetch chunk 0: diag (lane r = row r's word 0) + scores
  unsigned long long diag_cur = mbase[(size_t)t * NW + 0];
  uint32_t s_cur = __float_as_uint(sel_score[(size_t)b * SEL + t]);

  for (int chunk = 0; chunk < NCH; chunk++) {
    unsigned long long diag_nxt = 0;
    uint32_t s_nxt = 0;
    bool hasNext = (chunk + 1 < NCH);
    if (hasNext) {  // issue next chunk's prefetch before the serial body
      diag_nxt = mbase[(size_t)((chunk + 1) * 64 + t) * NW + (chunk + 1)];
      s_nxt = __float_as_uint(sel_score[(size_t)b * SEL + (chunk + 1) * 64 + t]);
    }
    unsigned long long finm = __ballot(s_cur != 0xFF800000u);  // finite rows
    int rmax = PRE_NMS - chunk * 64;
    if (rmax > 64) rmax = 64;
    unsigned long long alive = ~readlane_u64(removed, chunk);
    if (rmax < 64) alive &= (((unsigned long long)1 << rmax) - 1);
    unsigned long long keepm = 0ull;
    while (alive) {
      int r = __ffsll((long long)alive) - 1;
      unsigned long long rb = (unsigned long long)1 << r;
      keepm |= rb;
      alive &= ~rb;
      if ((finm >> r) & 1ull) {  // finite score: counted & output
        if (t == 0) keptList[kc] = (uint32_t)(chunk * 64 + r);
        kc++;
        if (kc == POST_NMS) goto writeout;
      }
      alive &= ~readlane_u64(diag_cur, r);  // forward in-chunk suppression
    }
    {  // fold: leaders' mask rows, 32 independent loads per batch, one wait
      const unsigned long long* rowbase = mbase + (size_t)chunk * 64 * NW;
      unsigned long long partial = 0ull;
      unsigned long long km = keepm;
      while (km) {
        int idx[32];
        unsigned long long kmb = km;
        int prev = __ffsll((long long)kmb) - 1;
#pragma unroll
        for (int q = 0; q < 32; q++) {  // extract up to 32 scalar indices
          int r = kmb ? (__ffsll((long long)kmb) - 1) : prev;
          idx[q] = r;
          prev = r;
          kmb &= kmb - 1;
        }
        km = kmb;
        unsigned long long w[32];
#pragma unroll
        for (int q = 0; q < 32; q++)  // independent coalesced 256B row loads
          w[q] = rowbase[(size_t)idx[q] * NW + tw];
#pragma unroll
        for (int s = 16; s >= 1; s >>= 1)  // tree OR
          for (int q = 0; q < s; q++) w[q] |= w[q + s];
        partial |= w[0];
      }
      removed |=
          partial | (unsigned long long)__shfl_xor((long long)partial, 32);
    }
    diag_cur = diag_nxt;
    s_cur = s_nxt;
  }
writeout:
  __syncthreads();
  for (int r = t; r < POST_NMS; r += 64) {
    float4 bx = make_float4(0.0f, 0.0f, 0.0f, 0.0f);
    float sc = 0.0f;
    if (r < kc) {
      int i = (int)keptList[r];
      bx = sel_box[(size_t)b * SEL + i];
      sc = sel_score[(size_t)b * SEL + i];
    }
    float* o = out + ((size_t)b * POST_NMS + r) * 5;
    o[0] = bx.x;
    o[1] = bx.y;
    o[2] = bx.z;
    o[3] = bx.w;
    o[4] = sc;
  }
}

extern "C" void kernel_launch(void* const* d_in, const int* in_sizes, int n_in,
                              void* d_out, int out_size, void* d_ws, size_t ws_size,
                              hipStream_t stream) {
  const float* anchors = (const float*)d_in[0];  // (A, 4)
  const float* deltas = (const float*)d_in[1];   // (B, A, 4)
  const float* scores = (const float*)d_in[2];   // (B, A)
  int A = in_sizes[0] / 4;
  int BA = in_sizes[2];
  int B = BA / A;
  float* out = (float*)d_out;

  char* ws = (char*)d_ws;
  size_t off = 0;
  uint32_t* keys = (uint32_t*)(ws + off);
  off += (size_t)BA * 4;
  uint32_t* chist = (uint32_t*)(ws + off);
  off += (size_t)B * 256 * 4;
  uint32_t* fhist = (uint32_t*)(ws + off);
  off += (size_t)B * 256 * 4;
  int* cbArr = (int*)(ws + off);
  off += (size_t)B * 4;
  uint32_t* cumArr = (uint32_t*)(ws + off);
  off += (size_t)B * 4;
  uint32_t* thresh = (uint32_t*)(ws + off);
  off += (size_t)B * 4;
  off = (off + 127) & ~(size_t)127;
  uint32_t* cnts = (uint32_t*)(ws + off);
  off += (size_t)B * CNT_STRIDE * 4;
  off = (off + 15) & ~(size_t)15;
  unsigned long long* cand_sort = (unsigned long long*)(ws + off);
  off += (size_t)B * CAP * 8;
  float4* sel_box = (float4*)(ws + off);
  off += (size_t)B * SEL * 16;
  float* sel_score = (float*)(ws + off);
  off += (size_t)B * SEL * 4;
  unsigned long long* mask = (unsigned long long*)(ws + off);
  off += (size_t)B * SEL * NW * 8;
  // total ~27 MB

  // Block geometry for per-batch streaming kernels: A = 261888 = 256*11*93.
  int chunks = (A % (256 * 11) == 0) ? 11 : 1;
  int bpb = (A + 256 * chunks - 1) / (256 * chunks);  // blocks per batch

  hipMemsetAsync(chist, 0, (size_t)B * 256 * 4 * 2, stream);  // chist+fhist
  k_decode<<<dim3(bpb, B), 256, 0, stream>>>((const float4*)anchors,
                                             (const float4*)deltas, scores,
                                             keys, chist, A, chunks);
  k_coarse<<<B, 256, 0, stream>>>(chist, cbArr, cumArr);
  k_fine<<<dim3(bpb, B), 256, 0, stream>>>(keys, cbArr, fhist, A, chunks);
  k_thresh<<<B, 256, 0, stream>>>(fhist, cbArr, cumArr, thresh, cnts);
  k_gather<<<dim3(bpb, B), 256, 0, stream>>>(keys, thresh, cnts, cand_sort, A,
                                             chunks);
  k_fillsel<<<dim3(SEL / 256, B), 256, 0, stream>>>(sel_box, sel_score);
  k_rank<<<dim3(CAP / 256, B), 256, 0, stream>>>(cand_sort, cnts,
                                                 (const float4*)anchors,
                                                 (const float4*)deltas,
                                                 sel_box, sel_score, A);
  k_nmsmask<<<dim3(NW, SEL / 64, B), 64, 0, stream>>>(sel_box, mask);
  k_scanout<<<B, 64, 0, stream>>>(sel_box, sel_score, mask, out);
}

// Round 11
// 386.590 us; speedup vs baseline: 1.2701x; 1.0484x over previous
//
#include <hip/hip_runtime.h>
#include <stdint.h>
#include <math.h>

// RPN proposal filtering: decode -> clip -> validity mask -> stable top-2000
// -> greedy NMS (IoU > 0.7) -> first 1000 kept -> (B, 1000, 5).
//
// R11: scanout's fold moved to global_load_lds DMA. R10 proved (VGPR_Count=40
// vs >=64 needed) that the register allocator serializes VGPR row loads into
// per-load vmcnt waits; the DMA path is fire-and-forget with ZERO VGPR cost,
// so all leader-row fetches stay in flight. One leader row = 64 lanes x 4B =
// 256B = exactly one DMA. Issued inside the resolve loop (overlaps memory
// with scalar resolve), one manual s_waitcnt vmcnt(0) (compiler can't see
// DMA->LDS deps), LDS OR-fold (2-way bank aliasing = free).

#define IMGF 1024.0f
#define PRE_NMS 2000
#define POST_NMS 1000
#define NMS_THR 0.7f
#define MIN_SZ 16.0f
#define CAP 4096          // candidate buffer per batch
#define SEL 2048          // padded selection stride (>= PRE_NMS)
#define NW (SEL / 64)     // 32 mask words per row
#define CNT_STRIDE 32     // u32s per batch for counters (128 B -> own line)
#define KEY_NEGINF 0x007FFFFFu  // f2key(-inf)
#define MAXCHUNK 12

// Order-preserving float -> u32 key (all floats incl. -inf totally ordered).
__device__ __forceinline__ uint32_t f2key(float f) {
  uint32_t u = __float_as_uint(f);
  return (u & 0x80000000u) ? ~u : (u | 0x80000000u);
}
__device__ __forceinline__ float key2f(uint32_t k) {
  uint32_t u = (k & 0x80000000u) ? (k & 0x7FFFFFFFu) : ~k;
  return __uint_as_float(u);
}

__device__ __forceinline__ unsigned long long readlane_u64(unsigned long long v,
                                                           int lane) {
  unsigned int lo = __builtin_amdgcn_readlane((unsigned int)v, lane);
  unsigned int hi = __builtin_amdgcn_readlane((unsigned int)(v >> 32), lane);
  return ((unsigned long long)hi << 32) | lo;
}

// Fire-and-forget global->LDS DMA: lane i's 4B lands at l + i*4.
__device__ __forceinline__ void dma_row_u32(const uint32_t* g, uint32_t* l) {
  __builtin_amdgcn_global_load_lds(
      (const __attribute__((address_space(1))) void*)g,
      (__attribute__((address_space(3))) void*)l, 4, 0, 0);
}

// Mirrors reference _decode + clip, fp32.
__device__ __forceinline__ float4 decode_clip(float4 anc, float4 dlt) {
  float aw = anc.z - anc.x;
  float ah = anc.w - anc.y;
  float ax = anc.x + 0.5f * aw;
  float ay = anc.y + 0.5f * ah;
  float dw = fminf(dlt.z, 4.0f);
  float dh = fminf(dlt.w, 4.0f);
  float px = dlt.x * aw + ax;
  float py = dlt.y * ah + ay;
  float pw = expf(dw) * aw;
  float ph = expf(dh) * ah;
  float x1 = px - 0.5f * pw, y1 = py - 0.5f * ph;
  float x2 = px + 0.5f * pw, y2 = py + 0.5f * ph;
  x1 = fminf(fmaxf(x1, 0.0f), IMGF);
  y1 = fminf(fmaxf(y1, 0.0f), IMGF);
  x2 = fminf(fmaxf(x2, 0.0f), IMGF);
  y2 = fminf(fmaxf(y2, 0.0f), IMGF);
  return make_float4(x1, y1, x2, y2);
}

// K1: decode -> masked-score key; per-block LDS coarse hist of key>>24
// (finite keys only), ballot-match wave aggregation, one aggregated global
// flush per block. grid = (bpb, B).
__global__ void k_decode(const float4* __restrict__ anchors,
                         const float4* __restrict__ deltas,
                         const float* __restrict__ scores,
                         uint32_t* __restrict__ keys,
                         uint32_t* __restrict__ chist,
                         int A, int chunks) {
  int b = blockIdx.y;
  int t = threadIdx.x;  // 256
  int lane = t & 63;
  __shared__ uint32_t shist[256];
  shist[t] = 0;
  __syncthreads();
  int base_a = blockIdx.x * (chunks * 256);
  for (int c = 0; c < chunks; c++) {
    int a = base_a + c * 256 + t;
    bool inb = a < A;
    int ac = inb ? a : (A - 1);
    size_t i = (size_t)b * A + ac;
    float4 box = decode_clip(anchors[ac], deltas[i]);
    bool valid = (box.z - box.x >= MIN_SZ) && (box.w - box.y >= MIN_SZ);
    float ms = valid ? scores[i] : -INFINITY;
    uint32_t k = f2key(ms);
    if (inb) keys[i] = k;
    uint32_t bucket = k >> 24;
    bool fin = inb && (k != KEY_NEGINF);
    // lanes with equal bucket -> one LDS atomic by the leader
    unsigned long long match = __ballot(fin);
#pragma unroll
    for (int bit = 0; bit < 8; bit++) {
      bool hb = (bucket >> bit) & 1;
      unsigned long long bb = __ballot(hb && fin);
      match &= hb ? bb : ~bb;
    }
    if (fin && (__ffsll((long long)match) - 1 == lane))
      atomicAdd(&shist[bucket], (uint32_t)__popcll(match));
  }
  __syncthreads();
  uint32_t v = shist[t];
  if (v) atomicAdd(&chist[b * 256 + t], v);
}

// K2: pick coarse bucket cb s.t. countAbove(cb) < PRE_NMS <= countAbove(cb)+chist[cb].
__global__ void k_coarse(const uint32_t* __restrict__ chist,
                         int* __restrict__ cbArr,
                         uint32_t* __restrict__ cumArr) {
  int b = blockIdx.x;
  int t = threadIdx.x;  // 256
  __shared__ uint32_t sA[256];
  sA[t] = chist[b * 256 + t];
  for (int d = 1; d < 256; d <<= 1) {  // inclusive suffix scan
    __syncthreads();
    uint32_t v = sA[t] + ((t + d < 256) ? sA[t + d] : 0u);
    __syncthreads();
    sA[t] = v;
  }
  __syncthreads();
  if (t == 0 && sA[0] < PRE_NMS) {  // degenerate: < PRE_NMS finite entries
    cbArr[b] = -1;
    cumArr[b] = 0;
  }
  uint32_t nxt = (t < 255) ? sA[t + 1] : 0u;
  if (sA[t] >= PRE_NMS && nxt < PRE_NMS) {
    cbArr[b] = t;
    cumArr[b] = nxt;  // count strictly above coarse bucket t
  }
}

// K3: fine hist of key bits[23:16] for elements whose coarse bucket == cb[b].
__global__ void k_fine(const uint32_t* __restrict__ keys,
                       const int* __restrict__ cbArr,
                       uint32_t* __restrict__ fhist,
                       int A, int chunks) {
  int b = blockIdx.y;
  int t = threadIdx.x;  // 256
  int cb = cbArr[b];
  if (cb < 0) return;
  __shared__ uint32_t shist[256];
  shist[t] = 0;
  __syncthreads();
  int base_a = blockIdx.x * (chunks * 256);
  uint32_t cbu = (uint32_t)cb;
  for (int c = 0; c < chunks; c++) {
    int a = base_a + c * 256 + t;
    if (a >= A) break;
    uint32_t k = keys[(size_t)b * A + a];
    if ((k >> 24) == cbu && k != KEY_NEGINF)
      atomicAdd(&shist[(k >> 16) & 0xFFu], 1u);
  }
  __syncthreads();
  uint32_t v = shist[t];
  if (v) atomicAdd(&fhist[b * 256 + t], v);
}

// K4: final 16-bit threshold beta = (cb<<8)|d:
// count(key>>16 > beta) < PRE_NMS <= count(key>>16 >= beta), finite keys only.
__global__ void k_thresh(const uint32_t* __restrict__ fhist,
                         const int* __restrict__ cbArr,
                         const uint32_t* __restrict__ cumArr,
                         uint32_t* __restrict__ thresh,
                         uint32_t* __restrict__ cnts) {
  int b = blockIdx.x;
  int t = threadIdx.x;  // 256
  __shared__ uint32_t sA[256];
  if (t < 2) cnts[b * CNT_STRIDE + t] = 0;
  int cb = cbArr[b];
  if (cb < 0) {
    if (t == 0) thresh[b] = 0u;
    return;
  }
  uint32_t cumAbove = cumArr[b];
  sA[t] = fhist[b * 256 + t];
  for (int d = 1; d < 256; d <<= 1) {
    __syncthreads();
    uint32_t v = sA[t] + ((t + d < 256) ? sA[t + d] : 0u);
    __syncthreads();
    sA[t] = v;
  }
  __syncthreads();
  uint32_t nxt = (t < 255) ? sA[t + 1] : 0u;
  if (cumAbove + sA[t] >= PRE_NMS && cumAbove + nxt < PRE_NMS)
    thresh[b] = (uint32_t)((cb << 8) | t);
}

// K5: gather candidate KEYS ONLY (8B each), block-aggregated atomics: one
// atomicAdd per category per block. Strictly-above fills [0, c1); ties fill
// from CAP-1 downward; overflow ties dropped (only above 2096 ties/batch).
__global__ void k_gather(const uint32_t* __restrict__ keys,
                         const uint32_t* __restrict__ thresh,
                         uint32_t* __restrict__ cnts,
                         unsigned long long* __restrict__ cand_sort,
                         int A, int chunks) {
  int b = blockIdx.y;
  int t = threadIdx.x;  // 256
  int lane = t & 63;
  int w = t >> 6;  // wave 0..3
  __shared__ unsigned long long s_mA[MAXCHUNK * 4], s_mT[MAXCHUNK * 4];
  __shared__ uint32_t s_offA[MAXCHUNK * 4], s_offT[MAXCHUNK * 4];
  __shared__ uint32_t s_cA[MAXCHUNK * 4], s_cT[MAXCHUNK * 4];
  __shared__ uint32_t s_baseA, s_baseT;
  uint32_t beta = thresh[b];
  uint32_t kreg[MAXCHUNK];
  int base_a = blockIdx.x * (chunks * 256);
  for (int c = 0; c < chunks; c++) {
    int a = base_a + c * 256 + t;
    bool inb = a < A;
    uint32_t k = inb ? keys[(size_t)b * A + a] : KEY_NEGINF;
    kreg[c] = k;
    uint32_t bk = k >> 16;
    bool fin = (k != KEY_NEGINF);
    unsigned long long mA = __ballot(fin && (bk > beta));
    unsigned long long mT = __ballot(fin && (bk == beta));
    if (lane == 0) {
      s_mA[c * 4 + w] = mA;
      s_mT[c * 4 + w] = mT;
    }
  }
  __syncthreads();
  if (t < chunks * 4) {
    s_cA[t] = (uint32_t)__popcll(s_mA[t]);
    s_cT[t] = (uint32_t)__popcll(s_mT[t]);
  }
  __syncthreads();
  if (t == 0) {  // serial scan over <=44 entries, then ONE atomic per category
    uint32_t accA = 0, accT = 0;
    for (int id = 0; id < chunks * 4; id++) {
      s_offA[id] = accA;
      accA += s_cA[id];
      s_offT[id] = accT;
      accT += s_cT[id];
    }
    s_baseA = accA ? atomicAdd(&cnts[b * CNT_STRIDE + 0], accA) : 0u;
    s_baseT = accT ? atomicAdd(&cnts[b * CNT_STRIDE + 1], accT) : 0u;
  }
  __syncthreads();
  uint32_t baseA = s_baseA, baseT = s_baseT;
  unsigned long long lower = ((unsigned long long)1 << lane) - 1;
  for (int c = 0; c < chunks; c++) {
    int id = c * 4 + w;
    unsigned long long mA = s_mA[id], mT = s_mT[id];
    bool above = (mA >> lane) & 1;
    bool tie = (mT >> lane) & 1;
    if (!(above || tie)) continue;
    int pos;
    if (above) {
      pos = (int)(baseA + s_offA[id] + (uint32_t)__popcll(mA & lower));
      if (pos >= PRE_NMS) continue;  // defensive; cannot happen
    } else {
      pos = CAP - 1 - (int)(baseT + s_offT[id] + (uint32_t)__popcll(mT & lower));
      if (pos < PRE_NMS) continue;  // drop overflow ties
    }
    int a = base_a + c * 256 + t;
    // sort key: (score_key desc, anchor index asc) via descending u64 order
    cand_sort[(size_t)b * CAP + pos] =
        ((unsigned long long)kreg[c] << 32) | (uint32_t)(~(uint32_t)a);
  }
}

// K6a: default-fill selection (pads for degenerate batches; overwritten by
// k_rank for every live rank < SEL). grid = (SEL/256, B).
__global__ void k_fillsel(float4* __restrict__ sel_box,
                          float* __restrict__ sel_score) {
  int b = blockIdx.y;
  int r = blockIdx.x * 256 + threadIdx.x;
  sel_score[(size_t)b * SEL + r] = -INFINITY;
  sel_box[(size_t)b * SEL + r] = make_float4(0.0f, 0.0f, 0.0f, 0.0f);
}

// K6b: enumeration sort. Keys are strictly distinct ((score_key, ~anchor)),
// so rank = #{keys > mine} is the exact descending-sorted position. Each
// thread owns one slot, streams the batch's live slots through LDS broadcast
// tiles, and (if rank < SEL) decodes its box from the embedded anchor index.
// grid = (CAP/256, B).
__global__ void k_rank(const unsigned long long* __restrict__ cand_sort,
                       const uint32_t* __restrict__ cnts,
                       const float4* __restrict__ anchors,
                       const float4* __restrict__ deltas,
                       float4* __restrict__ sel_box,
                       float* __restrict__ sel_score, int A) {
  int b = blockIdx.y;
  int t = threadIdx.x;  // 256
  uint32_t c1 = cnts[b * CNT_STRIDE + 0];
  if (c1 > PRE_NMS) c1 = PRE_NMS;
  uint32_t c2 = cnts[b * CNT_STRIDE + 1];
  if (c2 > CAP - PRE_NMS) c2 = CAP - PRE_NMS;
  int loTie = CAP - (int)c2;
  int bs = blockIdx.x * 256;
  if (bs >= (int)c1 && bs + 256 <= loTie) return;  // block fully in dead gap
  int s = bs + t;
  bool live = (s < (int)c1) || (s >= loTie);
  unsigned long long myKey = live ? cand_sort[(size_t)b * CAP + s] : 0ull;
  __shared__ unsigned long long tile[256];
  int rank = 0;
  for (int ts = 0; ts < CAP; ts += 256) {  // tile-skip is block-uniform
    if (ts >= (int)c1 && ts + 256 <= loTie) continue;
    int idx = ts + t;
    bool lv = (idx < (int)c1) || (idx >= loTie);
    __syncthreads();
    tile[t] = lv ? cand_sort[(size_t)b * CAP + idx] : 0ull;
    __syncthreads();
    if (live) {
#pragma unroll 8
      for (int j = 0; j < 256; j++) rank += (tile[j] > myKey) ? 1 : 0;
    }
  }
  if (live && rank < SEL) {
    uint32_t a = ~((uint32_t)myKey);
    float4 box = decode_clip(anchors[a], deltas[(size_t)b * A + a]);
    sel_score[(size_t)b * SEL + rank] = key2f((uint32_t)(myKey >> 32));
    sel_box[(size_t)b * SEL + rank] = box;
  }
}

// K7: suppression bitmask. mask[b][i][jb] bit jj set iff j = jb*64+jj > i,
// j < PRE_NMS, IoU(box_i, box_j) > NMS_THR. Rows in [PRE_NMS, SEL) zeroed
// so k_scanout never reads unwritten workspace.
__global__ void k_nmsmask(const float4* __restrict__ sel_box,
                          unsigned long long* __restrict__ mask) {
  int jb = blockIdx.x;  // col block
  int ib = blockIdx.y;  // row block
  int b = blockIdx.z;
  int t = threadIdx.x;  // 64
  int i = ib * 64 + t;
  if (jb < ib) {  // uniform per block; entire col tile is <= all rows
    mask[((size_t)b * SEL + i) * NW + jb] = 0ull;
    return;
  }
  __shared__ float4 cb[64];
  __shared__ float careb[64];
  int j0 = jb * 64;
  float4 cbx = sel_box[(size_t)b * SEL + j0 + t];
  cb[t] = cbx;
  careb[t] = (cbx.z - cbx.x) * (cbx.w - cbx.y);
  __syncthreads();
  if (i >= PRE_NMS) {  // pad rows: write zeros, never leave stale poison
    mask[((size_t)b * SEL + i) * NW + jb] = 0ull;
    return;
  }
  float4 a = sel_box[(size_t)b * SEL + i];
  float area_a = (a.z - a.x) * (a.w - a.y);
  unsigned long long bits = 0ull;
  int jmax = min(64, PRE_NMS - j0);
  for (int jj = 0; jj < jmax; jj++) {
    int j = j0 + jj;
    if (j <= i) continue;
    float4 bb = cb[jj];
    float ltx = fmaxf(a.x, bb.x), lty = fmaxf(a.y, bb.y);
    float rbx = fminf(a.z, bb.z), rby = fminf(a.w, bb.w);
    float w = fmaxf(rbx - ltx, 0.0f), hgt = fmaxf(rby - lty, 0.0f);
    float inter = w * hgt;
    float iou = inter / (area_a + careb[jj] - inter + 1e-6f);
    if (iou > NMS_THR) bits |= (1ull << jj);
  }
  mask[((size_t)b * SEL + i) * NW + jb] = bits;
}

// K8 (R11): one wave per batch, DMA fold. Per chunk: diag + scores prefetched
// (register loads); resolve via scalar ffs/readlane, issuing one
// global_load_lds per LEADER as discovered (fire-and-forget, 0 VGPR, 256B
// row -> lds + nl*256); one manual vmcnt(0) drain; LDS OR-fold into
// `removed`. Early exit at POST_NMS kept.
__global__ void __launch_bounds__(64, 1) k_scanout(
    const float4* __restrict__ sel_box,
    const float* __restrict__ sel_score,
    const unsigned long long* __restrict__ mask,
    float* __restrict__ out) {
  int b = blockIdx.x;
  int t = threadIdx.x;  // 64 = 1 wave
  int tw = t & 31;
  __shared__ uint32_t sRows[64 * 64];  // 16 KB DMA landing pad (64 rows max)
  __shared__ uint32_t keptList[POST_NMS];
  const unsigned long long* mbase = mask + (size_t)b * SEL * NW;
  unsigned long long removed = 0ull;  // lane t holds word tw (dup per half)
  int kc = 0;
  const int NCH = (PRE_NMS + 63) / 64;  // 32

  // prefetch chunk 0: diag (lane r = row r's word 0) + scores
  unsigned long long diag_cur = mbase[(size_t)t * NW + 0];
  uint32_t s_cur = __float_as_uint(sel_score[(size_t)b * SEL + t]);

  for (int chunk = 0; chunk < NCH; chunk++) {
    unsigned long long diag_nxt = 0;
    uint32_t s_nxt = 0;
    bool hasNext = (chunk + 1 < NCH);
    if (hasNext) {  // issue next chunk's prefetch before the serial body
      diag_nxt = mbase[(size_t)((chunk + 1) * 64 + t) * NW + (chunk + 1)];
      s_nxt = __float_as_uint(sel_score[(size_t)b * SEL + (chunk + 1) * 64 + t]);
    }
    unsigned long long finm = __ballot(s_cur != 0xFF800000u);  // finite rows
    int rmax = PRE_NMS - chunk * 64;
    if (rmax > 64) rmax = 64;
    unsigned long long alive = ~readlane_u64(removed, chunk);
    if (rmax < 64) alive &= (((unsigned long long)1 << rmax) - 1);
    const uint32_t* rowbase32 =
        (const uint32_t*)(mbase + (size_t)chunk * 64 * NW);
    int nl = 0;
    bool full = false;
    while (alive) {
      int r = __ffsll((long long)alive) - 1;
      unsigned long long rb = (unsigned long long)1 << r;
      alive &= ~rb;
      // DMA row r (256B) -> sRows + nl*64 u32; lane t's 4B at +t*4.
      dma_row_u32(rowbase32 + (size_t)r * 64 + t, sRows + nl * 64);
      nl++;
      if ((finm >> r) & 1ull) {  // finite score: counted & output
        if (t == 0) keptList[kc] = (uint32_t)(chunk * 64 + r);
        kc++;
        if (kc == POST_NMS) {
          full = true;
          break;
        }
      }
      alive &= ~readlane_u64(diag_cur, r);  // forward in-chunk suppression
    }
    if (full) break;
    // manual drain: compiler cannot see the DMA->LDS dependency
    __builtin_amdgcn_s_waitcnt(0x0f70);  // vmcnt(0), lgkm/exp untouched
    {
      unsigned long long partial = 0ull;
      const unsigned long long* sR = (const unsigned long long*)sRows;
      for (int q = 0; q < nl; q++) partial |= sR[q * 32 + tw];
      removed |=
          partial | (unsigned long long)__shfl_xor((long long)partial, 32);
    }
    diag_cur = diag_nxt;
    s_cur = s_nxt;
  }
  __builtin_amdgcn_s_waitcnt(0x0f70);  // drain any outstanding DMA
  __syncthreads();
  for (int r = t; r < POST_NMS; r += 64) {
    float4 bx = make_float4(0.0f, 0.0f, 0.0f, 0.0f);
    float sc = 0.0f;
    if (r < kc) {
      int i = (int)keptList[r];
      bx = sel_box[(size_t)b * SEL + i];
      sc = sel_score[(size_t)b * SEL + i];
    }
    float* o = out + ((size_t)b * POST_NMS + r) * 5;
    o[0] = bx.x;
    o[1] = bx.y;
    o[2] = bx.z;
    o[3] = bx.w;
    o[4] = sc;
  }
}

extern "C" void kernel_launch(void* const* d_in, const int* in_sizes, int n_in,
                              void* d_out, int out_size, void* d_ws, size_t ws_size,
                              hipStream_t stream) {
  const float* anchors = (const float*)d_in[0];  // (A, 4)
  const float* deltas = (const float*)d_in[1];   // (B, A, 4)
  const float* scores = (const float*)d_in[2];   // (B, A)
  int A = in_sizes[0] / 4;
  int BA = in_sizes[2];
  int B = BA / A;
  float* out = (float*)d_out;

  char* ws = (char*)d_ws;
  size_t off = 0;
  uint32_t* keys = (uint32_t*)(ws + off);
  off += (size_t)BA * 4;
  uint32_t* chist = (uint32_t*)(ws + off);
  off += (size_t)B * 256 * 4;
  uint32_t* fhist = (uint32_t*)(ws + off);
  off += (size_t)B * 256 * 4;
  int* cbArr = (int*)(ws + off);
  off += (size_t)B * 4;
  uint32_t* cumArr = (uint32_t*)(ws + off);
  off += (size_t)B * 4;
  uint32_t* thresh = (uint32_t*)(ws + off);
  off += (size_t)B * 4;
  off = (off + 127) & ~(size_t)127;
  uint32_t* cnts = (uint32_t*)(ws + off);
  off += (size_t)B * CNT_STRIDE * 4;
  off = (off + 15) & ~(size_t)15;
  unsigned long long* cand_sort = (unsigned long long*)(ws + off);
  off += (size_t)B * CAP * 8;
  float4* sel_box = (float4*)(ws + off);
  off += (size_t)B * SEL * 16;
  float* sel_score = (float*)(ws + off);
  off += (size_t)B * SEL * 4;
  unsigned long long* mask = (unsigned long long*)(ws + off);
  off += (size_t)B * SEL * NW * 8;
  // total ~27 MB

  // Block geometry for per-batch streaming kernels: A = 261888 = 256*11*93.
  int chunks = (A % (256 * 11) == 0) ? 11 : 1;
  int bpb = (A + 256 * chunks - 1) / (256 * chunks);  // blocks per batch

  hipMemsetAsync(chist, 0, (size_t)B * 256 * 4 * 2, stream);  // chist+fhist
  k_decode<<<dim3(bpb, B), 256, 0, stream>>>((const float4*)anchors,
                                             (const float4*)deltas, scores,
                                             keys, chist, A, chunks);
  k_coarse<<<B, 256, 0, stream>>>(chist, cbArr, cumArr);
  k_fine<<<dim3(bpb, B), 256, 0, stream>>>(keys, cbArr, fhist, A, chunks);
  k_thresh<<<B, 256, 0, stream>>>(fhist, cbArr, cumArr, thresh, cnts);
  k_gather<<<dim3(bpb, B), 256, 0, stream>>>(keys, thresh, cnts, cand_sort, A,
                                             chunks);
  k_fillsel<<<dim3(SEL / 256, B), 256, 0, stream>>>(sel_box, sel_score);
  k_rank<<<dim3(CAP / 256, B), 256, 0, stream>>>(cand_sort, cnts,
                                                 (const float4*)anchors,
                                                 (const float4*)deltas,
                                                 sel_box, sel_score, A);
  k_nmsmask<<<dim3(NW, SEL / 64, B), 64, 0, stream>>>(sel_box, mask);
  k_scanout<<<B, 64, 0, stream>>>(sel_box, sel_score, mask, out);
}